// Round 11
// baseline (2704.778 us; speedup 1.0000x reference)
//
#include <hip/hip_runtime.h>
#include <cstddef>

// ---------------------------------------------------------------------------
// RelGraphConv GNN, 10 layers. Round 19: single-buffered B + 4 blocks/CU.
//   R18's counted vmcnt was ~null -> drain wasn't the stall; outstanding
//   A-bytes is (R17 evidence). R19: B (weights, L2-resident ~200cy) doesn't
//   need double-buffering; Bs[2]->Bs[1] cuts LDS 48->40 KB -> 4 blocks/CU
//   (32 waves/CU at VGPR 60), outstanding A-reads/CU 72->~128 KB.
//   Pipeline per step (exact counts, simulated):
//     prologue: A(0)->As[0], B(0)->Bs, A(1)->As[1]   [5 insts in flight]
//     step k: vmcnt(2) [A(k),B(k) landed; A(k+1) in flight]; s_barrier;
//             MFMA(As[k&1], Bs); s_barrier [Bs free];
//             issue B(k+1) then A(k+2)->As[k&1].
// Keeps: W_loop fold into W_u1, col-fastest grid, fast_tanh, parallel scan.
// N=100000, E=600000, F=64, H=128, R=8.
// ---------------------------------------------------------------------------

#define HID 128
#define NREL 8
#define NL 10

typedef __attribute__((ext_vector_type(8))) __bf16 bf16x8;
typedef __attribute__((ext_vector_type(4))) float f32x4;

__device__ __forceinline__ float fast_tanh(float x) {
  float cx = fminf(fmaxf(x, -10.f), 10.f);
  float z = exp2f(cx * 2.8853900817779268f);
  return (z - 1.f) * __builtin_amdgcn_rcpf(z + 1.f);
}

// --- batched transpose + f32->bf16: tile z: W[zi][K][Nc] -> Wt[zo][Nc][K] ---
__global__ __launch_bounds__(256) void k_transpose(const float* __restrict__ W,
                                                   __bf16* __restrict__ Wt,
                                                   int K, int Nc,
                                                   int inDiv, int inScale, int inOff,
                                                   int outDiv, int outScale, int outOff) {
  __shared__ float t[32][33];
  int z = blockIdx.z;
  int zi = (z / inDiv) * inScale + (z % inDiv) + inOff;
  int zo = (z / outDiv) * outScale + (z % outDiv) + outOff;
  const float* Wz = W + (size_t)zi * K * Nc;
  __bf16* Wtz = Wt + (size_t)zo * K * Nc;
  int n0 = blockIdx.x * 32, k0 = blockIdx.y * 32;
#pragma unroll
  for (int i = 0; i < 4; i++) {
    int k = k0 + threadIdx.y + i * 8;
    int n = n0 + threadIdx.x;
    t[threadIdx.y + i * 8][threadIdx.x] = Wz[(size_t)k * Nc + n];
  }
  __syncthreads();
#pragma unroll
  for (int i = 0; i < 4; i++) {
    int n = n0 + threadIdx.y + i * 8;
    int k = k0 + threadIdx.x;
    Wtz[(size_t)n * K + k] = (__bf16)t[threadIdx.x][threadIdx.y + i * 8];
  }
}

// --- fold W_loop into wt_u1 (k<128 rows): wt[n][k] = Wu1[k][n] + sum_j
//     Wloop[k][j]*Wu1[128+j][n]. Runs AFTER k_transpose(W_u1).
__global__ __launch_bounds__(256) void k_fold_wu1(const float* __restrict__ Wu1,
                                                  const float* __restrict__ Wloop,
                                                  __bf16* __restrict__ wt) {
  int l = blockIdx.y;
  int n0 = blockIdx.x * 32;
  const float* wu1 = Wu1 + (size_t)l * 256 * 256;
  const float* wl = Wloop + (size_t)l * 128 * 128;
  __bf16* wtl = wt + (size_t)l * 256 * 256;
  __shared__ float bot[128][33];
  for (int t = threadIdx.x; t < 128 * 32; t += 256) {
    int j = t >> 5, c = t & 31;
    bot[j][c] = wu1[(size_t)(128 + j) * 256 + n0 + c];
  }
  __syncthreads();
  int k = threadIdx.x & 127;
  int half = threadIdx.x >> 7;
  float acc[16];
#pragma unroll
  for (int c = 0; c < 16; c++) acc[c] = 0.f;
  for (int j = 0; j < 128; j++) {
    float w = wl[(size_t)k * 128 + j];
#pragma unroll
    for (int c = 0; c < 16; c++) acc[c] += w * bot[j][half * 16 + c];
  }
#pragma unroll
  for (int c = 0; c < 16; c++) {
    int n = n0 + half * 16 + c;
    wtl[(size_t)n * 256 + k] = (__bf16)(wu1[(size_t)k * 256 + n] + acc[c]);
  }
}

// --- f32 -> bf16 elementwise (n4 = count/4) ---
__global__ __launch_bounds__(256) void k_cvt(const float* __restrict__ x,
                                             __bf16* __restrict__ y, int n4) {
  int i = blockIdx.x * 256 + threadIdx.x;
  if (i < n4) {
    float4 f = ((const float4*)x)[i];
    __bf16 o[4] = {(__bf16)f.x, (__bf16)f.y, (__bf16)f.z, (__bf16)f.w};
    *(uint2*)(y + (size_t)i * 4) = *(uint2*)o;
  }
}

// ===================== dst-CSR build (once per launch) ======================
__global__ __launch_bounds__(256) void k_zero(int* __restrict__ p, int n) {
  for (int i = blockIdx.x * 256 + threadIdx.x; i < n; i += gridDim.x * 256) p[i] = 0;
}

__global__ __launch_bounds__(256) void k_hist_row(const int* __restrict__ dst,
                                                  int E, int* __restrict__ rowCnt) {
  int e = blockIdx.x * 256 + threadIdx.x;
  if (e < E) atomicAdd(&rowCnt[dst[e]], 1);
}

// --- hierarchical prefix scan over rowCnt[0..nb) ---------------------------
__global__ __launch_bounds__(256) void k_scan_part(const int* __restrict__ rowCnt,
                                                   int nb, int* __restrict__ thrPre,
                                                   int* __restrict__ blkSum) {
  __shared__ int sdata[256];
  int tid = threadIdx.x;
  int gtid = blockIdx.x * 256 + tid;
  int tot = gridDim.x * 256;
  int chunk = (nb + tot - 1) / tot;
  int lo = gtid * chunk, hi = min(nb, lo + chunk);
  int s = 0;
  for (int i = lo; i < hi; i++) s += rowCnt[i];
  sdata[tid] = s;
  __syncthreads();
#pragma unroll
  for (int off = 1; off < 256; off <<= 1) {
    int t = (tid >= off) ? sdata[tid - off] : 0;
    __syncthreads();
    sdata[tid] += t;
    __syncthreads();
  }
  thrPre[gtid] = sdata[tid] - s;
  if (tid == 255) blkSum[blockIdx.x] = sdata[255];
}

__global__ __launch_bounds__(256) void k_scan_mid(const int* __restrict__ blkSum,
                                                  int nblk, int nb,
                                                  int* __restrict__ blkOff,
                                                  int* __restrict__ rowStart) {
  __shared__ int part[256];
  int tid = threadIdx.x;
  part[tid] = (tid < nblk) ? blkSum[tid] : 0;
  __syncthreads();
  if (tid == 0) {
    int a = 0;
    for (int i = 0; i < nblk; i++) { int v = part[i]; part[i] = a; a += v; }
    rowStart[nb] = a;
  }
  __syncthreads();
  if (tid < nblk) blkOff[tid] = part[tid];
}

__global__ __launch_bounds__(256) void k_scan_fin(const int* __restrict__ rowCnt,
                                                  int nb,
                                                  const int* __restrict__ thrPre,
                                                  const int* __restrict__ blkOff,
                                                  int* __restrict__ rowStart,
                                                  int* __restrict__ rowCur) {
  int tid = threadIdx.x;
  int gtid = blockIdx.x * 256 + tid;
  int tot = gridDim.x * 256;
  int chunk = (nb + tot - 1) / tot;
  int lo = gtid * chunk, hi = min(nb, lo + chunk);
  int run = blkOff[blockIdx.x] + thrPre[gtid];
  for (int i = lo; i < hi; i++) {
    rowStart[i] = run;
    rowCur[i] = run;
    run += rowCnt[i];
  }
}

// pack: src (17 bits) | etype << 17
__global__ __launch_bounds__(256) void k_place_row(const int* __restrict__ et,
                                                   const int* __restrict__ src,
                                                   const int* __restrict__ dst,
                                                   int* __restrict__ rowCur,
                                                   int* __restrict__ epk, int E) {
  int e = blockIdx.x * 256 + threadIdx.x;
  if (e < E) {
    int p = atomicAdd(&rowCur[dst[e]], 1);
    epk[p] = src[e] | (et[e] << 17);
  }
}

// ========================= CSR segment-sum kernel ===========================
__global__ __launch_bounds__(256) void seg_sum(
    const __bf16* __restrict__ Z, const int* __restrict__ rowStart,
    const int* __restrict__ epk, const float* __restrict__ b_rel_l,
    __bf16* __restrict__ msgb, int N, int relBase, int zW) {
  int t16 = threadIdx.x & 15;
  int d = blockIdx.x * 16 + (threadIdx.x >> 4);
  if (d >= N) return;

  float acc[8];
  if (b_rel_l) {
#pragma unroll
    for (int z = 0; z < 8; z++) acc[z] = b_rel_l[t16 * 8 + z];
  } else {
    bf16x8 mv = *(const bf16x8*)(msgb + (size_t)d * HID + t16 * 8);
#pragma unroll
    for (int z = 0; z < 8; z++) acc[z] = (float)mv[z];
  }

  int lo = rowStart[d], hi = rowStart[d + 1];
  for (int e = lo; e < hi; e++) {
    int p = epk[e];
    int rr = (p >> 17) - relBase;
    if ((unsigned)rr < 4u) {
      bf16x8 v = *(const bf16x8*)(Z + (size_t)(p & 0x1FFFF) * zW + rr * HID + t16 * 8);
#pragma unroll
      for (int z = 0; z < 8; z++) acc[z] += (float)v[z];
    }
  }

  bf16x8 o;
#pragma unroll
  for (int z = 0; z < 8; z++) o[z] = (__bf16)acc[z];
  *(bf16x8*)(msgb + (size_t)d * HID + t16 * 8) = o;
}

// ---------------------------------------------------------------------------
// DMA-staged bf16 MFMA GEMM, 512 threads, 256x128 C-tile, BK=32.
//   A double-buffered (HBM stream), B single-buffered (L2-resident weights).
//   LDS = 2*16 + 8 = 40 KB -> 4 blocks/CU; counted vmcnt keeps 2 A-stages
//   in flight. Per wave per stage: A = 2 DMA insts, B = 1 DMA inst.
// ---------------------------------------------------------------------------
template <int K, int K0, int MINW>
__global__ __launch_bounds__(512, MINW) void gemm_lds(
    const __bf16* __restrict__ A0, const __bf16* __restrict__ A1,
    const __bf16* __restrict__ Bt, const float* __restrict__ bias,
    __bf16* __restrict__ Cb, float* __restrict__ Cf,
    int M, int Nc, int act) {
  constexpr int NS = K / 32;
  constexpr int NS0 = K0 / 32;
  constexpr int K1 = (K - K0) > 0 ? (K - K0) : 1;
  __shared__ __bf16 As[2][256][32];
  __shared__ __bf16 Bs[128][32];

  const int tid = threadIdx.x;
  const int m0 = blockIdx.y * 256;
  const int bn0 = blockIdx.x * 128;
  const int w = tid >> 6;       // 0..7
  const int lane = tid & 63;

  // A: 1024 chunks (16B): chunk c -> row c>>2, slot c&3. wave w: c = w*128 + j*64 + lane
  const int cA0 = w * 128 + lane;
  const int rA0 = cA0 >> 2, sA0 = cA0 & 3;
  const int cA1 = cA0 + 64;
  const int rA1 = cA1 >> 2, sA1 = cA1 & 3;
  // B: 512 chunks: wave w: c = w*64 + lane
  const int cB = w * 64 + lane;
  const int rB = cB >> 2, sB = cB & 3;

  auto stage_B = [&](int ks) {
    const __bf16* g = Bt + (size_t)(bn0 + rB) * K + ks * 32 + sB * 8;
    __builtin_amdgcn_global_load_lds(
        (const __attribute__((address_space(1))) void*)g,
        (__attribute__((address_space(3))) void*)(&Bs[0][0] + (size_t)w * 512),
        16, 0, 0);
  };
  auto stage_A = [&](int b, int ks) {
    if (ks < NS0) {
      const __bf16* g0 = A0 + (size_t)(m0 + rA0) * K0 + ks * 32 + sA0 * 8;
      __builtin_amdgcn_global_load_lds(
          (const __attribute__((address_space(1))) void*)g0,
          (__attribute__((address_space(3))) void*)(&As[b][0][0] + (size_t)(w * 2 + 0) * 512),
          16, 0, 0);
      const __bf16* g1 = A0 + (size_t)(m0 + rA1) * K0 + ks * 32 + sA1 * 8;
      __builtin_amdgcn_global_load_lds(
          (const __attribute__((address_space(1))) void*)g1,
          (__attribute__((address_space(3))) void*)(&As[b][0][0] + (size_t)(w * 2 + 1) * 512),
          16, 0, 0);
    } else {
      const __bf16* g0 = A1 + (size_t)(m0 + rA0) * K1 + (ks - NS0) * 32 + sA0 * 8;
      __builtin_amdgcn_global_load_lds(
          (const __attribute__((address_space(1))) void*)g0,
          (__attribute__((address_space(3))) void*)(&As[b][0][0] + (size_t)(w * 2 + 0) * 512),
          16, 0, 0);
      const __bf16* g1 = A1 + (size_t)(m0 + rA1) * K1 + (ks - NS0) * 32 + sA1 * 8;
      __builtin_amdgcn_global_load_lds(
          (const __attribute__((address_space(1))) void*)g1,
          (__attribute__((address_space(3))) void*)(&As[b][0][0] + (size_t)(w * 2 + 1) * 512),
          16, 0, 0);
    }
  };

  const int ml = lane & 15, q = lane >> 4;
  const int wr = (w >> 1) * 64;   // 0,64,128,192
  const int wc = (w & 1) * 64;    // 0,64

  f32x4 acc[4][4];
#pragma unroll
  for (int i = 0; i < 4; i++)
#pragma unroll
    for (int j = 0; j < 4; j++)
#pragma unroll
      for (int r = 0; r < 4; r++) acc[i][j][r] = 0.f;

  // prologue: A(0), B(0), A(1)  -> issue-order queue [A0,A0,B0,A1,A1]
  stage_A(0, 0);
  stage_B(0);
  if (NS > 1) stage_A(1, 1);

#pragma unroll
  for (int ks = 0; ks < NS; ks++) {
    const int cur = ks & 1;
    // wait A(ks)+B(ks) landed; A(ks+1)'s 2 insts stay in flight
    if (ks + 1 < NS) asm volatile("s_waitcnt vmcnt(2)" ::: "memory");
    else             asm volatile("s_waitcnt vmcnt(0)" ::: "memory");
    asm volatile("s_barrier" ::: "memory");  // all waves' stage(ks) landed

    bf16x8 af[4], bfr[4];
#pragma unroll
    for (int i = 0; i < 4; i++)
      af[i] = *(const bf16x8*)(&As[cur][wr + i * 16 + ml][q * 8]);
#pragma unroll
    for (int j = 0; j < 4; j++)
      bfr[j] = *(const bf16x8*)(&Bs[wc + j * 16 + ml][q * 8]);
#pragma unroll
    for (int i = 0; i < 4; i++)
#pragma unroll
      for (int j = 0; j < 4; j++)
        acc[i][j] = __builtin_amdgcn_mfma_f32_16x16x32_bf16(af[i], bfr[j],
                                                            acc[i][j], 0, 0, 0);

    asm volatile("s_barrier" ::: "memory");  // all waves done reading Bs/As[cur]
    if (ks + 1 < NS) stage_B(ks + 1);        // refill Bs (issued BEFORE next A)
    if (ks + 2 < NS) stage_A(cur, ks + 2);   // refill freed A buffer
  }

  // --- epilogue ---
#pragma unroll
  for (int i = 0; i < 4; i++) {
#pragma unroll
    for (int r = 0; r < 4; r++) {
      int grow = m0 + wr + i * 16 + q * 4 + r;
      if (grow >= M) continue;
#pragma unroll
      for (int j = 0; j < 4; j++) {
        int col = bn0 + wc + j * 16 + ml;
        float v = acc[i][j][r];
        if (bias) v += bias[col];
        if (act) v = fast_tanh(v);
        if (Cb) Cb[(size_t)grow * Nc + col] = (__bf16)v;
        if (Cf) Cf[(size_t)grow * Nc + col] = v;
      }
    }
  }
}

extern "C" void kernel_launch(void* const* d_in, const int* in_sizes, int n_in,
                              void* d_out, int out_size, void* d_ws, size_t ws_size,
                              hipStream_t stream) {
  const float* feats  = (const float*)d_in[0];
  const int*   src    = (const int*)d_in[1];
  const int*   dst    = (const int*)d_in[2];
  const int*   etype  = (const int*)d_in[3];
  const float* W_in   = (const float*)d_in[4];
  const float* b_in   = (const float*)d_in[5];
  const float* W_rel  = (const float*)d_in[6];
  const float* W_loop = (const float*)d_in[7];
  const float* b_rel  = (const float*)d_in[8];
  const float* W_u1   = (const float*)d_in[9];
  const float* b_u1   = (const float*)d_in[10];
  const float* W_u2   = (const float*)d_in[11];
  const float* b_u2   = (const float*)d_in[12];

  const int E = in_sizes[1];
  const int N = in_sizes[0] / 64;
  const int TS = HID * HID;

  // --- workspace layout (~210 MB) ---
  __bf16* xb0  = (__bf16*)d_ws;                       // N*128
  __bf16* xb1  = xb0 + (size_t)N * HID;               // N*128
  __bf16* msgb = xb1 + (size_t)N * HID;               // N*128
  __bf16* U    = msgb + (size_t)N * HID;              // N*640 (Z | mid | featsb)
  __bf16* Z    = U;
  __bf16* mid  = U;
  __bf16* featsb = U;
  __bf16* wt_in = U + (size_t)N * 640;                // [128][64]
  __bf16* wt_z0 = wt_in + 128 * 64;                   // [10][4][128][128]
  __bf16* wt_z1 = wt_z0 + (size_t)10 * 4 * TS;        // [10][4][128][128]
  __bf16* wt_u1 = wt_z1 + (size_t)10 * 4 * TS;        // [10][256][256]
  __bf16* wt_u2 = wt_u1 + (size_t)10 * 256 * 256;     // [10][128][384]
  int* rowCnt   = (int*)(wt_u2 + (size_t)10 * 128 * 384); // N
  int* rowStart = rowCnt + N;                         // N+1
  int* rowCur   = rowStart + N + 1;                   // N
  int* epk      = rowCur + N;                         // E
  int* thrPre   = epk + E;                            // 256*256
  int* blkSum   = thrPre + 256 * 256;                 // 256
  int* blkOff   = blkSum + 256;                       // 256

  // --- weight transpose+convert ---
  k_transpose<<<dim3(4, 2, 1), dim3(32, 8), 0, stream>>>(W_in, wt_in, 64, 128,
                                                         1, 1, 0, 1, 1, 0);
  k_transpose<<<dim3(4, 4, 40), dim3(32, 8), 0, stream>>>(W_rel, wt_z0, 128, 128,
                                                          4, 8, 0, 4, 4, 0);
  k_transpose<<<dim3(4, 4, 40), dim3(32, 8), 0, stream>>>(W_rel, wt_z1, 128, 128,
                                                          4, 8, 4, 4, 4, 0);
  k_transpose<<<dim3(8, 8, 10), dim3(32, 8), 0, stream>>>(W_u1, wt_u1, 256, 256,
                                                          1, 1, 0, 1, 1, 0);
  k_fold_wu1<<<dim3(8, 10), dim3(256), 0, stream>>>(W_u1, W_loop, wt_u1);
  k_transpose<<<dim3(4, 12, 10), dim3(32, 8), 0, stream>>>(W_u2, wt_u2, 384, 128,
                                                           1, 1, 0, 1, 1, 0);
  k_cvt<<<(N * 64 / 4 + 255) / 256, 256, 0, stream>>>(feats, featsb, N * 64 / 4);

  // --- dst-CSR build ---
  k_zero<<<128, 256, 0, stream>>>(rowCnt, N);
  k_hist_row<<<(E + 255) / 256, 256, 0, stream>>>(dst, E, rowCnt);
  k_scan_part<<<256, 256, 0, stream>>>(rowCnt, N, thrPre, blkSum);
  k_scan_mid<<<1, 256, 0, stream>>>(blkSum, 256, N, blkOff, rowStart);
  k_scan_fin<<<256, 256, 0, stream>>>(rowCnt, N, thrPre, blkOff, rowStart, rowCur);
  k_place_row<<<(E + 255) / 256, 256, 0, stream>>>(etype, src, dst, rowCur, epk, E);

  const dim3 blk(512);
  const int gm = (N + 255) / 256;
  const dim3 gseg((N + 15) / 16);

  // input projection: x0 = tanh(featsb @ W_in + b_in)
  gemm_lds<64, 64, 4><<<dim3(1, gm), blk, 0, stream>>>(
      featsb, featsb, wt_in, b_in, xb0, nullptr, N, HID, 1);

  for (int l = 0; l < NL; l++) {
    const __bf16* xin = (l & 1) ? xb1 : xb0;
    __bf16* xout = (l & 1) ? xb0 : xb1;

    // pass 0: Z = xin @ [W_0..3]  (N x 512; W_loop folded into wt_u1)
    gemm_lds<128, 128, 4><<<dim3(4, gm), blk, 0, stream>>>(
        xin, xin, wt_z0 + (size_t)l * 4 * TS, nullptr, Z, nullptr, N, 512, 0);
    // seg0: msg = b_rel + sum(r<4) edges
    seg_sum<<<gseg, dim3(256), 0, stream>>>(Z, rowStart, epk,
                                            b_rel + (size_t)l * HID,
                                            msgb, N, 0, 512);
    // pass 1: Z = xin @ [W_4..7]  (N x 512)
    gemm_lds<128, 128, 4><<<dim3(4, gm), blk, 0, stream>>>(
        xin, xin, wt_z1 + (size_t)l * 4 * TS, nullptr, Z, nullptr, N, 512, 0);
    // seg1: msg += sum(r>=4) edges
    seg_sum<<<gseg, dim3(256), 0, stream>>>(Z, rowStart, epk, nullptr,
                                            msgb, N, 4, 512);

    // mid = tanh([x | msg] @ Wu1_eff[l] + b_u1[l])   (mid aliases Z)
    gemm_lds<256, 128, 4><<<dim3(2, gm), blk, 0, stream>>>(
        xin, msgb, wt_u1 + (size_t)l * 256 * 256, b_u1 + (size_t)l * 256,
        mid, nullptr, N, 256, 1);

    // x' = tanh([x | mid] @ W_u2[l] + b_u2[l]); last layer -> f32 d_out
    gemm_lds<384, 128, 4><<<dim3(1, gm), blk, 0, stream>>>(
        xin, mid, wt_u2 + (size_t)l * HID * 384, b_u2 + (size_t)l * HID,
        (l == NL - 1) ? nullptr : xout,
        (l == NL - 1) ? (float*)d_out : nullptr,
        N, HID, 1);
  }
}

// Round 12
// 2379.040 us; speedup vs baseline: 1.1369x; 1.1369x over previous
//
#include <hip/hip_runtime.h>
#include <cstddef>

// ---------------------------------------------------------------------------
// RelGraphConv GNN, 10 layers. Round 20: R18 base + XCD swizzle + seg unroll.
//   R19 (single-buf B) null/neg: U1's grid (782 blocks = 3.05/CU) binds
//   occupancy, not LDS; and at 72 KB/CU outstanding the latency ceiling is
//   ~49 TB/s >> HBM, so the 1.8 TB/s plateau is the memory path itself —
//   best remaining candidate: A-stripe re-reads are CROSS-XCD L3 hits
//   (col-fastest grid round-robins same-stripe blocks across XCDs).
//   R20a: T1 bijective XCD-chunked remap inside gemm_lds (m204 formula) —
//         same-m-stripe blocks land on one XCD -> A re-reads are local L2.
//   R20b: seg_sum 4-wide edge unroll, unconditional clamped loads (addr
//         always valid via rr&3; accumulate predicated) — mean degree 3,
//         old loop was serialized L3 latency per edge.
// Keeps: R18 counted-vmcnt 512-thr 256x128 BK=32 GEMM, W_loop fold,
//        col-fastest grid, fast_tanh, parallel scan.
// N=100000, E=600000, F=64, H=128, R=8.
// ---------------------------------------------------------------------------

#define HID 128
#define NREL 8
#define NL 10

typedef __attribute__((ext_vector_type(8))) __bf16 bf16x8;
typedef __attribute__((ext_vector_type(4))) float f32x4;

__device__ __forceinline__ float fast_tanh(float x) {
  float cx = fminf(fmaxf(x, -10.f), 10.f);
  float z = exp2f(cx * 2.8853900817779268f);
  return (z - 1.f) * __builtin_amdgcn_rcpf(z + 1.f);
}

// --- batched transpose + f32->bf16: tile z: W[zi][K][Nc] -> Wt[zo][Nc][K] ---
__global__ __launch_bounds__(256) void k_transpose(const float* __restrict__ W,
                                                   __bf16* __restrict__ Wt,
                                                   int K, int Nc,
                                                   int inDiv, int inScale, int inOff,
                                                   int outDiv, int outScale, int outOff) {
  __shared__ float t[32][33];
  int z = blockIdx.z;
  int zi = (z / inDiv) * inScale + (z % inDiv) + inOff;
  int zo = (z / outDiv) * outScale + (z % outDiv) + outOff;
  const float* Wz = W + (size_t)zi * K * Nc;
  __bf16* Wtz = Wt + (size_t)zo * K * Nc;
  int n0 = blockIdx.x * 32, k0 = blockIdx.y * 32;
#pragma unroll
  for (int i = 0; i < 4; i++) {
    int k = k0 + threadIdx.y + i * 8;
    int n = n0 + threadIdx.x;
    t[threadIdx.y + i * 8][threadIdx.x] = Wz[(size_t)k * Nc + n];
  }
  __syncthreads();
#pragma unroll
  for (int i = 0; i < 4; i++) {
    int n = n0 + threadIdx.y + i * 8;
    int k = k0 + threadIdx.x;
    Wtz[(size_t)n * K + k] = (__bf16)t[threadIdx.x][threadIdx.y + i * 8];
  }
}

// --- fold W_loop into wt_u1 (k<128 rows): wt[n][k] = Wu1[k][n] + sum_j
//     Wloop[k][j]*Wu1[128+j][n]. Runs AFTER k_transpose(W_u1).
__global__ __launch_bounds__(256) void k_fold_wu1(const float* __restrict__ Wu1,
                                                  const float* __restrict__ Wloop,
                                                  __bf16* __restrict__ wt) {
  int l = blockIdx.y;
  int n0 = blockIdx.x * 32;
  const float* wu1 = Wu1 + (size_t)l * 256 * 256;
  const float* wl = Wloop + (size_t)l * 128 * 128;
  __bf16* wtl = wt + (size_t)l * 256 * 256;
  __shared__ float bot[128][33];
  for (int t = threadIdx.x; t < 128 * 32; t += 256) {
    int j = t >> 5, c = t & 31;
    bot[j][c] = wu1[(size_t)(128 + j) * 256 + n0 + c];
  }
  __syncthreads();
  int k = threadIdx.x & 127;
  int half = threadIdx.x >> 7;
  float acc[16];
#pragma unroll
  for (int c = 0; c < 16; c++) acc[c] = 0.f;
  for (int j = 0; j < 128; j++) {
    float w = wl[(size_t)k * 128 + j];
#pragma unroll
    for (int c = 0; c < 16; c++) acc[c] += w * bot[j][half * 16 + c];
  }
#pragma unroll
  for (int c = 0; c < 16; c++) {
    int n = n0 + half * 16 + c;
    wtl[(size_t)n * 256 + k] = (__bf16)(wu1[(size_t)k * 256 + n] + acc[c]);
  }
}

// --- f32 -> bf16 elementwise (n4 = count/4) ---
__global__ __launch_bounds__(256) void k_cvt(const float* __restrict__ x,
                                             __bf16* __restrict__ y, int n4) {
  int i = blockIdx.x * 256 + threadIdx.x;
  if (i < n4) {
    float4 f = ((const float4*)x)[i];
    __bf16 o[4] = {(__bf16)f.x, (__bf16)f.y, (__bf16)f.z, (__bf16)f.w};
    *(uint2*)(y + (size_t)i * 4) = *(uint2*)o;
  }
}

// ===================== dst-CSR build (once per launch) ======================
__global__ __launch_bounds__(256) void k_zero(int* __restrict__ p, int n) {
  for (int i = blockIdx.x * 256 + threadIdx.x; i < n; i += gridDim.x * 256) p[i] = 0;
}

__global__ __launch_bounds__(256) void k_hist_row(const int* __restrict__ dst,
                                                  int E, int* __restrict__ rowCnt) {
  int e = blockIdx.x * 256 + threadIdx.x;
  if (e < E) atomicAdd(&rowCnt[dst[e]], 1);
}

// --- hierarchical prefix scan over rowCnt[0..nb) ---------------------------
__global__ __launch_bounds__(256) void k_scan_part(const int* __restrict__ rowCnt,
                                                   int nb, int* __restrict__ thrPre,
                                                   int* __restrict__ blkSum) {
  __shared__ int sdata[256];
  int tid = threadIdx.x;
  int gtid = blockIdx.x * 256 + tid;
  int tot = gridDim.x * 256;
  int chunk = (nb + tot - 1) / tot;
  int lo = gtid * chunk, hi = min(nb, lo + chunk);
  int s = 0;
  for (int i = lo; i < hi; i++) s += rowCnt[i];
  sdata[tid] = s;
  __syncthreads();
#pragma unroll
  for (int off = 1; off < 256; off <<= 1) {
    int t = (tid >= off) ? sdata[tid - off] : 0;
    __syncthreads();
    sdata[tid] += t;
    __syncthreads();
  }
  thrPre[gtid] = sdata[tid] - s;
  if (tid == 255) blkSum[blockIdx.x] = sdata[255];
}

__global__ __launch_bounds__(256) void k_scan_mid(const int* __restrict__ blkSum,
                                                  int nblk, int nb,
                                                  int* __restrict__ blkOff,
                                                  int* __restrict__ rowStart) {
  __shared__ int part[256];
  int tid = threadIdx.x;
  part[tid] = (tid < nblk) ? blkSum[tid] : 0;
  __syncthreads();
  if (tid == 0) {
    int a = 0;
    for (int i = 0; i < nblk; i++) { int v = part[i]; part[i] = a; a += v; }
    rowStart[nb] = a;
  }
  __syncthreads();
  if (tid < nblk) blkOff[tid] = part[tid];
}

__global__ __launch_bounds__(256) void k_scan_fin(const int* __restrict__ rowCnt,
                                                  int nb,
                                                  const int* __restrict__ thrPre,
                                                  const int* __restrict__ blkOff,
                                                  int* __restrict__ rowStart,
                                                  int* __restrict__ rowCur) {
  int tid = threadIdx.x;
  int gtid = blockIdx.x * 256 + tid;
  int tot = gridDim.x * 256;
  int chunk = (nb + tot - 1) / tot;
  int lo = gtid * chunk, hi = min(nb, lo + chunk);
  int run = blkOff[blockIdx.x] + thrPre[gtid];
  for (int i = lo; i < hi; i++) {
    rowStart[i] = run;
    rowCur[i] = run;
    run += rowCnt[i];
  }
}

// pack: src (17 bits) | etype << 17
__global__ __launch_bounds__(256) void k_place_row(const int* __restrict__ et,
                                                   const int* __restrict__ src,
                                                   const int* __restrict__ dst,
                                                   int* __restrict__ rowCur,
                                                   int* __restrict__ epk, int E) {
  int e = blockIdx.x * 256 + threadIdx.x;
  if (e < E) {
    int p = atomicAdd(&rowCur[dst[e]], 1);
    epk[p] = src[e] | (et[e] << 17);
  }
}

// ========================= CSR segment-sum kernel ===========================
// 16 lanes per dst row. 4-wide edge unroll: all 4 Z-loads issue before any
// accumulate (concurrent L3 latency). Loads are unconditional with clamped
// address (slot = rr&3, always in-bounds); accumulate predicated.
__global__ __launch_bounds__(256) void seg_sum(
    const __bf16* __restrict__ Z, const int* __restrict__ rowStart,
    const int* __restrict__ epk, const float* __restrict__ b_rel_l,
    __bf16* __restrict__ msgb, int N, int relBase, int zW) {
  int t16 = threadIdx.x & 15;
  int d = blockIdx.x * 16 + (threadIdx.x >> 4);
  if (d >= N) return;

  float acc[8];
  if (b_rel_l) {
#pragma unroll
    for (int z = 0; z < 8; z++) acc[z] = b_rel_l[t16 * 8 + z];
  } else {
    bf16x8 mv = *(const bf16x8*)(msgb + (size_t)d * HID + t16 * 8);
#pragma unroll
    for (int z = 0; z < 8; z++) acc[z] = (float)mv[z];
  }

  const int lo = rowStart[d], hi = rowStart[d + 1];
  for (int e0 = lo; e0 < hi; e0 += 4) {
    bf16x8 v[4];
    int take[4];
#pragma unroll
    for (int u = 0; u < 4; u++) {
      int e = e0 + u;
      int in = e < hi;
      int p = epk[in ? e : lo];          // safe index re-read when OOB
      int rr = (p >> 17) - relBase;      // may be out of [0,4)
      int slot = rr & 3;                 // clamped: address always valid
      v[u] = *(const bf16x8*)(Z + (size_t)(p & 0x1FFFF) * zW + slot * HID + t16 * 8);
      take[u] = in && ((unsigned)rr < 4u);
    }
#pragma unroll
    for (int u = 0; u < 4; u++) {
      if (take[u]) {
#pragma unroll
        for (int z = 0; z < 8; z++) acc[z] += (float)v[u][z];
      }
    }
  }

  bf16x8 o;
#pragma unroll
  for (int z = 0; z < 8; z++) o[z] = (__bf16)acc[z];
  *(bf16x8*)(msgb + (size_t)d * HID + t16 * 8) = o;
}

// ---------------------------------------------------------------------------
// DMA-staged bf16 MFMA GEMM (R18-proven): 512 threads, 256x128 C-tile, BK=32,
// 2 buffers, counted-vmcnt. NEW: bijective XCD-chunked block remap (m204) so
// blocks sharing an A m-stripe run on the same XCD (A re-reads hit local L2).
// ---------------------------------------------------------------------------
template <int K, int K0, int MINW>
__global__ __launch_bounds__(512, MINW) void gemm_lds(
    const __bf16* __restrict__ A0, const __bf16* __restrict__ A1,
    const __bf16* __restrict__ Bt, const float* __restrict__ bias,
    __bf16* __restrict__ Cb, float* __restrict__ Cf,
    int M, int Nc, int act) {
  constexpr int NS = K / 32;
  constexpr int NS0 = K0 / 32;
  constexpr int K1 = (K - K0) > 0 ? (K - K0) : 1;
  __shared__ __bf16 As[2][256][32];
  __shared__ __bf16 Bs[2][128][32];

  const int tid = threadIdx.x;

  // --- XCD-chunked bijective remap (m204): hw id -> work index wk such that
  //     each XCD (id%8, round-robin dispatch) owns a contiguous wk chunk ->
  //     same-m-stripe blocks (consecutive wk) share one XCD's L2.
  int colt, mrow;
  {
    const int gx = gridDim.x;
    const int nb = gx * gridDim.y;
    const int id = blockIdx.x + blockIdx.y * gx;
    const int q = nb >> 3, r = nb & 7;
    const int xcd = id & 7, i = id >> 3;
    const int wk = (xcd < r) ? (xcd * (q + 1) + i)
                             : (r * (q + 1) + (xcd - r) * q + i);
    colt = wk % gx;
    mrow = wk / gx;
  }
  const int m0 = mrow * 256;
  const int bn0 = colt * 128;

  const int w = tid >> 6;       // 0..7
  const int lane = tid & 63;

  // A: 1024 chunks (16B): chunk c -> row c>>2, slot c&3. wave w: c = w*128 + j*64 + lane
  const int cA0 = w * 128 + lane;
  const int rA0 = cA0 >> 2, sA0 = cA0 & 3;
  const int cA1 = cA0 + 64;
  const int rA1 = cA1 >> 2, sA1 = cA1 & 3;
  // B: 512 chunks: wave w: c = w*64 + lane
  const int cB = w * 64 + lane;
  const int rB = cB >> 2, sB = cB & 3;

  auto stage_step = [&](int b, int ks) {
    // B tile (rows = output cols, stride K): 1 inst/wave
    {
      const __bf16* g = Bt + (size_t)(bn0 + rB) * K + ks * 32 + sB * 8;
      __builtin_amdgcn_global_load_lds(
          (const __attribute__((address_space(1))) void*)g,
          (__attribute__((address_space(3))) void*)(&Bs[b][0][0] + (size_t)w * 512),
          16, 0, 0);
    }
    // A tile: 2 insts/wave; concat segment select (wave-uniform per step)
    if (ks < NS0) {
      const __bf16* g0 = A0 + (size_t)(m0 + rA0) * K0 + ks * 32 + sA0 * 8;
      __builtin_amdgcn_global_load_lds(
          (const __attribute__((address_space(1))) void*)g0,
          (__attribute__((address_space(3))) void*)(&As[b][0][0] + (size_t)(w * 2 + 0) * 512),
          16, 0, 0);
      const __bf16* g1 = A0 + (size_t)(m0 + rA1) * K0 + ks * 32 + sA1 * 8;
      __builtin_amdgcn_global_load_lds(
          (const __attribute__((address_space(1))) void*)g1,
          (__attribute__((address_space(3))) void*)(&As[b][0][0] + (size_t)(w * 2 + 1) * 512),
          16, 0, 0);
    } else {
      const __bf16* g0 = A1 + (size_t)(m0 + rA0) * K1 + (ks - NS0) * 32 + sA0 * 8;
      __builtin_amdgcn_global_load_lds(
          (const __attribute__((address_space(1))) void*)g0,
          (__attribute__((address_space(3))) void*)(&As[b][0][0] + (size_t)(w * 2 + 0) * 512),
          16, 0, 0);
      const __bf16* g1 = A1 + (size_t)(m0 + rA1) * K1 + (ks - NS0) * 32 + sA1 * 8;
      __builtin_amdgcn_global_load_lds(
          (const __attribute__((address_space(1))) void*)g1,
          (__attribute__((address_space(3))) void*)(&As[b][0][0] + (size_t)(w * 2 + 1) * 512),
          16, 0, 0);
    }
  };

  const int ml = lane & 15, q2 = lane >> 4;
  const int wr = (w >> 1) * 64;   // 0,64,128,192
  const int wc = (w & 1) * 64;    // 0,64

  f32x4 acc[4][4];
#pragma unroll
  for (int i = 0; i < 4; i++)
#pragma unroll
    for (int j = 0; j < 4; j++)
#pragma unroll
      for (int r = 0; r < 4; r++) acc[i][j][r] = 0.f;

  // prologue: two stages in flight (6 DMA insts/wave)
  stage_step(0, 0);
  if (NS > 1) stage_step(1, 1);

#pragma unroll
  for (int ks = 0; ks < NS; ks++) {
    const int cur = ks & 1;
    // own stage(ks) landed; stage(ks+1)'s 3 DMAs stay in flight
    if (ks + 1 < NS) asm volatile("s_waitcnt vmcnt(3)" ::: "memory");
    else             asm volatile("s_waitcnt vmcnt(0)" ::: "memory");
    asm volatile("s_barrier" ::: "memory");  // all waves' stage(ks) landed

    bf16x8 af[4], bfr[4];
#pragma unroll
    for (int i = 0; i < 4; i++)
      af[i] = *(const bf16x8*)(&As[cur][wr + i * 16 + ml][q2 * 8]);
#pragma unroll
    for (int j = 0; j < 4; j++)
      bfr[j] = *(const bf16x8*)(&Bs[cur][wc + j * 16 + ml][q2 * 8]);
#pragma unroll
    for (int i = 0; i < 4; i++)
#pragma unroll
      for (int j = 0; j < 4; j++)
        acc[i][j] = __builtin_amdgcn_mfma_f32_16x16x32_bf16(af[i], bfr[j],
                                                            acc[i][j], 0, 0, 0);

    asm volatile("s_barrier" ::: "memory");  // all waves done reading buf[cur]
    if (ks + 2 < NS) stage_step(cur, ks + 2);  // refill freed buffer, stays in flight
  }

  // --- epilogue ---
#pragma unroll
  for (int i = 0; i < 4; i++) {
#pragma unroll
    for (int r = 0; r < 4; r++) {
      int grow = m0 + wr + i * 16 + q2 * 4 + r;
      if (grow >= M) continue;
#pragma unroll
      for (int j = 0; j < 4; j++) {
        int col = bn0 + wc + j * 16 + ml;
        float v = acc[i][j][r];
        if (bias) v += bias[col];
        if (act) v = fast_tanh(v);
        if (Cb) Cb[(size_t)grow * Nc + col] = (__bf16)v;
        if (Cf) Cf[(size_t)grow * Nc + col] = v;
      }
    }
  }
}

extern "C" void kernel_launch(void* const* d_in, const int* in_sizes, int n_in,
                              void* d_out, int out_size, void* d_ws, size_t ws_size,
                              hipStream_t stream) {
  const float* feats  = (const float*)d_in[0];
  const int*   src    = (const int*)d_in[1];
  const int*   dst    = (const int*)d_in[2];
  const int*   etype  = (const int*)d_in[3];
  const float* W_in   = (const float*)d_in[4];
  const float* b_in   = (const float*)d_in[5];
  const float* W_rel  = (const float*)d_in[6];
  const float* W_loop = (const float*)d_in[7];
  const float* b_rel  = (const float*)d_in[8];
  const float* W_u1   = (const float*)d_in[9];
  const float* b_u1   = (const float*)d_in[10];
  const float* W_u2   = (const float*)d_in[11];
  const float* b_u2   = (const float*)d_in[12];

  const int E = in_sizes[1];
  const int N = in_sizes[0] / 64;
  const int TS = HID * HID;

  // --- workspace layout (~210 MB) ---
  __bf16* xb0  = (__bf16*)d_ws;                       // N*128
  __bf16* xb1  = xb0 + (size_t)N * HID;               // N*128
  __bf16* msgb = xb1 + (size_t)N * HID;               // N*128
  __bf16* U    = msgb + (size_t)N * HID;              // N*640 (Z | mid | featsb)
  __bf16* Z    = U;
  __bf16* mid  = U;
  __bf16* featsb = U;
  __bf16* wt_in = U + (size_t)N * 640;                // [128][64]
  __bf16* wt_z0 = wt_in + 128 * 64;                   // [10][4][128][128]
  __bf16* wt_z1 = wt_z0 + (size_t)10 * 4 * TS;        // [10][4][128][128]
  __bf16* wt_u1 = wt_z1 + (size_t)10 * 4 * TS;        // [10][256][256]
  __bf16* wt_u2 = wt_u1 + (size_t)10 * 256 * 256;     // [10][128][384]
  int* rowCnt   = (int*)(wt_u2 + (size_t)10 * 128 * 384); // N
  int* rowStart = rowCnt + N;                         // N+1
  int* rowCur   = rowStart + N + 1;                   // N
  int* epk      = rowCur + N;                         // E
  int* thrPre   = epk + E;                            // 256*256
  int* blkSum   = thrPre + 256 * 256;                 // 256
  int* blkOff   = blkSum + 256;                       // 256

  // --- weight transpose+convert ---
  k_transpose<<<dim3(4, 2, 1), dim3(32, 8), 0, stream>>>(W_in, wt_in, 64, 128,
                                                         1, 1, 0, 1, 1, 0);
  k_transpose<<<dim3(4, 4, 40), dim3(32, 8), 0, stream>>>(W_rel, wt_z0, 128, 128,
                                                          4, 8, 0, 4, 4, 0);
  k_transpose<<<dim3(4, 4, 40), dim3(32, 8), 0, stream>>>(W_rel, wt_z1, 128, 128,
                                                          4, 8, 4, 4, 4, 0);
  k_transpose<<<dim3(8, 8, 10), dim3(32, 8), 0, stream>>>(W_u1, wt_u1, 256, 256,
                                                          1, 1, 0, 1, 1, 0);
  k_fold_wu1<<<dim3(8, 10), dim3(256), 0, stream>>>(W_u1, W_loop, wt_u1);
  k_transpose<<<dim3(4, 12, 10), dim3(32, 8), 0, stream>>>(W_u2, wt_u2, 384, 128,
                                                           1, 1, 0, 1, 1, 0);
  k_cvt<<<(N * 64 / 4 + 255) / 256, 256, 0, stream>>>(feats, featsb, N * 64 / 4);

  // --- dst-CSR build ---
  k_zero<<<128, 256, 0, stream>>>(rowCnt, N);
  k_hist_row<<<(E + 255) / 256, 256, 0, stream>>>(dst, E, rowCnt);
  k_scan_part<<<256, 256, 0, stream>>>(rowCnt, N, thrPre, blkSum);
  k_scan_mid<<<1, 256, 0, stream>>>(blkSum, 256, N, blkOff, rowStart);
  k_scan_fin<<<256, 256, 0, stream>>>(rowCnt, N, thrPre, blkOff, rowStart, rowCur);
  k_place_row<<<(E + 255) / 256, 256, 0, stream>>>(etype, src, dst, rowCur, epk, E);

  const dim3 blk(512);
  const int gm = (N + 255) / 256;
  const dim3 gseg((N + 15) / 16);

  // input projection: x0 = tanh(featsb @ W_in + b_in)
  gemm_lds<64, 64, 2><<<dim3(1, gm), blk, 0, stream>>>(
      featsb, featsb, wt_in, b_in, xb0, nullptr, N, HID, 1);

  for (int l = 0; l < NL; l++) {
    const __bf16* xin = (l & 1) ? xb1 : xb0;
    __bf16* xout = (l & 1) ? xb0 : xb1;

    // pass 0: Z = xin @ [W_0..3]  (N x 512; W_loop folded into wt_u1)
    gemm_lds<128, 128, 2><<<dim3(4, gm), blk, 0, stream>>>(
        xin, xin, wt_z0 + (size_t)l * 4 * TS, nullptr, Z, nullptr, N, 512, 0);
    // seg0: msg = b_rel + sum(r<4) edges
    seg_sum<<<gseg, dim3(256), 0, stream>>>(Z, rowStart, epk,
                                            b_rel + (size_t)l * HID,
                                            msgb, N, 0, 512);
    // pass 1: Z = xin @ [W_4..7]  (N x 512)
    gemm_lds<128, 128, 2><<<dim3(4, gm), blk, 0, stream>>>(
        xin, xin, wt_z1 + (size_t)l * 4 * TS, nullptr, Z, nullptr, N, 512, 0);
    // seg1: msg += sum(r>=4) edges
    seg_sum<<<gseg, dim3(256), 0, stream>>>(Z, rowStart, epk, nullptr,
                                            msgb, N, 4, 512);

    // mid = tanh([x | msg] @ Wu1_eff[l] + b_u1[l])   (mid aliases Z)
    gemm_lds<256, 128, 2><<<dim3(2, gm), blk, 0, stream>>>(
        xin, msgb, wt_u1 + (size_t)l * 256 * 256, b_u1 + (size_t)l * 256,
        mid, nullptr, N, 256, 1);

    // x' = tanh([x | mid] @ W_u2[l] + b_u2[l]); last layer -> f32 d_out
    gemm_lds<384, 128, 2><<<dim3(1, gm), blk, 0, stream>>>(
        xin, mid, wt_u2 + (size_t)l * HID * 384, b_u2 + (size_t)l * HID,
        (l == NL - 1) ? nullptr : xout,
        (l == NL - 1) ? (float*)d_out : nullptr,
        N, HID, 1);
  }
}

// Round 13
// 2294.133 us; speedup vs baseline: 1.1790x; 1.0370x over previous
//
#include <hip/hip_runtime.h>
#include <cstddef>

// ---------------------------------------------------------------------------
// RelGraphConv GNN, 10 layers. Round 21: per-relation src compaction.
//   R20 (XCD swizzle + seg unroll) confirmed: 2613 -> 2379 us, U1 FETCH
//   halved. Remaining algebraic waste: ~47% of Z rows are never read
//   (P[node is src of rel r] = 1-e^-0.75 = 53%). R21: per-rel compact Z.
//     prep: F[r*N+src]=1 per edge -> hierarchical scan -> rank P ->
//           srcOf gather table; epk stores compact zrow (19b) | half<<19.
//     pass: gemm_gather — per-rel gathered-A GEMM over ~53% of rows
//           (gather via per-lane global_load_lds src addresses; indices
//           cached once per block; early-exit past cnt).
//     seg: reads Zc[zrow*128] directly (simpler; full 256B rows).
//   U1/U2/proj keep the proven R20 gemm_lds (counted-vmcnt + XCD remap).
// Keeps: W_loop fold, fast_tanh, parallel scan, 4-wide seg unroll.
// N=100000, E=600000, F=64, H=128, R=8.
// ---------------------------------------------------------------------------

#define HID 128
#define NREL 8
#define NL 10

typedef __attribute__((ext_vector_type(8))) __bf16 bf16x8;
typedef __attribute__((ext_vector_type(4))) float f32x4;

__device__ __forceinline__ float fast_tanh(float x) {
  float cx = fminf(fmaxf(x, -10.f), 10.f);
  float z = exp2f(cx * 2.8853900817779268f);
  return (z - 1.f) * __builtin_amdgcn_rcpf(z + 1.f);
}

// --- batched transpose + f32->bf16: tile z: W[zi][K][Nc] -> Wt[zo][Nc][K] ---
__global__ __launch_bounds__(256) void k_transpose(const float* __restrict__ W,
                                                   __bf16* __restrict__ Wt,
                                                   int K, int Nc,
                                                   int inDiv, int inScale, int inOff,
                                                   int outDiv, int outScale, int outOff) {
  __shared__ float t[32][33];
  int z = blockIdx.z;
  int zi = (z / inDiv) * inScale + (z % inDiv) + inOff;
  int zo = (z / outDiv) * outScale + (z % outDiv) + outOff;
  const float* Wz = W + (size_t)zi * K * Nc;
  __bf16* Wtz = Wt + (size_t)zo * K * Nc;
  int n0 = blockIdx.x * 32, k0 = blockIdx.y * 32;
#pragma unroll
  for (int i = 0; i < 4; i++) {
    int k = k0 + threadIdx.y + i * 8;
    int n = n0 + threadIdx.x;
    t[threadIdx.y + i * 8][threadIdx.x] = Wz[(size_t)k * Nc + n];
  }
  __syncthreads();
#pragma unroll
  for (int i = 0; i < 4; i++) {
    int n = n0 + threadIdx.y + i * 8;
    int k = k0 + threadIdx.x;
    Wtz[(size_t)n * K + k] = (__bf16)t[threadIdx.x][threadIdx.y + i * 8];
  }
}

// --- fold W_loop into wt_u1 (k<128 rows) ---
__global__ __launch_bounds__(256) void k_fold_wu1(const float* __restrict__ Wu1,
                                                  const float* __restrict__ Wloop,
                                                  __bf16* __restrict__ wt) {
  int l = blockIdx.y;
  int n0 = blockIdx.x * 32;
  const float* wu1 = Wu1 + (size_t)l * 256 * 256;
  const float* wl = Wloop + (size_t)l * 128 * 128;
  __bf16* wtl = wt + (size_t)l * 256 * 256;
  __shared__ float bot[128][33];
  for (int t = threadIdx.x; t < 128 * 32; t += 256) {
    int j = t >> 5, c = t & 31;
    bot[j][c] = wu1[(size_t)(128 + j) * 256 + n0 + c];
  }
  __syncthreads();
  int k = threadIdx.x & 127;
  int half = threadIdx.x >> 7;
  float acc[16];
#pragma unroll
  for (int c = 0; c < 16; c++) acc[c] = 0.f;
  for (int j = 0; j < 128; j++) {
    float w = wl[(size_t)k * 128 + j];
#pragma unroll
    for (int c = 0; c < 16; c++) acc[c] += w * bot[j][half * 16 + c];
  }
#pragma unroll
  for (int c = 0; c < 16; c++) {
    int n = n0 + half * 16 + c;
    wtl[(size_t)n * 256 + k] = (__bf16)(wu1[(size_t)k * 256 + n] + acc[c]);
  }
}

// --- f32 -> bf16 elementwise (n4 = count/4) ---
__global__ __launch_bounds__(256) void k_cvt(const float* __restrict__ x,
                                             __bf16* __restrict__ y, int n4) {
  int i = blockIdx.x * 256 + threadIdx.x;
  if (i < n4) {
    float4 f = ((const float4*)x)[i];
    __bf16 o[4] = {(__bf16)f.x, (__bf16)f.y, (__bf16)f.z, (__bf16)f.w};
    *(uint2*)(y + (size_t)i * 4) = *(uint2*)o;
  }
}

// ===================== prep kernels (once per launch) =======================
__global__ __launch_bounds__(256) void k_zero(int* __restrict__ p, int n) {
  for (int i = blockIdx.x * 256 + threadIdx.x; i < n; i += gridDim.x * 256) p[i] = 0;
}

__global__ __launch_bounds__(256) void k_hist_row(const int* __restrict__ dst,
                                                  int E, int* __restrict__ rowCnt) {
  int e = blockIdx.x * 256 + threadIdx.x;
  if (e < E) atomicAdd(&rowCnt[dst[e]], 1);
}

// flag active (rel, src) pairs; half0 = rels 0-3, half1 = rels 4-7
__global__ __launch_bounds__(256) void k_flag(const int* __restrict__ et,
                                              const int* __restrict__ src,
                                              int E, int N,
                                              int* __restrict__ F0,
                                              int* __restrict__ F1) {
  int e = blockIdx.x * 256 + threadIdx.x;
  if (e < E) {
    int r = et[e];
    (r < 4 ? F0 : F1)[(r & 3) * N + src[e]] = 1;
  }
}

// scatter node ids to compact-row table
__global__ __launch_bounds__(256) void k_srcof(const int* __restrict__ F,
                                               const int* __restrict__ P,
                                               int n, int N, int* __restrict__ srcOf) {
  int i = blockIdx.x * 256 + threadIdx.x;
  if (i < n && F[i]) srcOf[P[i]] = i % N;
}

// --- hierarchical prefix scan over cnt[0..nb) -------------------------------
__global__ __launch_bounds__(256) void k_scan_part(const int* __restrict__ cntArr,
                                                   int nb, int* __restrict__ thrPre,
                                                   int* __restrict__ blkSum) {
  __shared__ int sdata[256];
  int tid = threadIdx.x;
  int gtid = blockIdx.x * 256 + tid;
  int tot = gridDim.x * 256;
  int chunk = (nb + tot - 1) / tot;
  int lo = gtid * chunk, hi = min(nb, lo + chunk);
  int s = 0;
  for (int i = lo; i < hi; i++) s += cntArr[i];
  sdata[tid] = s;
  __syncthreads();
#pragma unroll
  for (int off = 1; off < 256; off <<= 1) {
    int t = (tid >= off) ? sdata[tid - off] : 0;
    __syncthreads();
    sdata[tid] += t;
    __syncthreads();
  }
  thrPre[gtid] = sdata[tid] - s;
  if (tid == 255) blkSum[blockIdx.x] = sdata[255];
}

__global__ __launch_bounds__(256) void k_scan_mid(const int* __restrict__ blkSum,
                                                  int nblk, int nb,
                                                  int* __restrict__ blkOff,
                                                  int* __restrict__ pre) {
  __shared__ int part[256];
  int tid = threadIdx.x;
  part[tid] = (tid < nblk) ? blkSum[tid] : 0;
  __syncthreads();
  if (tid == 0) {
    int a = 0;
    for (int i = 0; i < nblk; i++) { int v = part[i]; part[i] = a; a += v; }
    pre[nb] = a;
  }
  __syncthreads();
  if (tid < nblk) blkOff[tid] = part[tid];
}

__global__ __launch_bounds__(256) void k_scan_fin(const int* __restrict__ cntArr,
                                                  int nb,
                                                  const int* __restrict__ thrPre,
                                                  const int* __restrict__ blkOff,
                                                  int* __restrict__ pre,
                                                  int* __restrict__ cur) {
  int tid = threadIdx.x;
  int gtid = blockIdx.x * 256 + tid;
  int tot = gridDim.x * 256;
  int chunk = (nb + tot - 1) / tot;
  int lo = gtid * chunk, hi = min(nb, lo + chunk);
  int run = blkOff[blockIdx.x] + thrPre[gtid];
  for (int i = lo; i < hi; i++) {
    pre[i] = run;
    if (cur) cur[i] = run;
    run += cntArr[i];
  }
}

// pack: compact zrow (19 bits) | half << 19
__global__ __launch_bounds__(256) void k_place_row(const int* __restrict__ et,
                                                   const int* __restrict__ src,
                                                   const int* __restrict__ dst,
                                                   const int* __restrict__ P0,
                                                   const int* __restrict__ P1,
                                                   int* __restrict__ rowCur,
                                                   int* __restrict__ epk, int E, int N) {
  int e = blockIdx.x * 256 + threadIdx.x;
  if (e < E) {
    int p = atomicAdd(&rowCur[dst[e]], 1);
    int r = et[e];
    int half = r >> 2;
    const int* P = half ? P1 : P0;
    int zrow = P[(r & 3) * N + src[e]];
    epk[p] = zrow | (half << 19);
  }
}

// ========================= CSR segment-sum kernel ===========================
// 16 lanes per dst row; 4-wide edge unroll. Zc rows are compact (128 wide).
__global__ __launch_bounds__(256) void seg_sum(
    const __bf16* __restrict__ Zc, const int* __restrict__ rowStart,
    const int* __restrict__ epk, const float* __restrict__ b_rel_l,
    __bf16* __restrict__ msgb, int N, int half) {
  int t16 = threadIdx.x & 15;
  int d = blockIdx.x * 16 + (threadIdx.x >> 4);
  if (d >= N) return;

  float acc[8];
  if (b_rel_l) {
#pragma unroll
    for (int z = 0; z < 8; z++) acc[z] = b_rel_l[t16 * 8 + z];
  } else {
    bf16x8 mv = *(const bf16x8*)(msgb + (size_t)d * HID + t16 * 8);
#pragma unroll
    for (int z = 0; z < 8; z++) acc[z] = (float)mv[z];
  }

  const int lo = rowStart[d], hi = rowStart[d + 1];
  for (int e0 = lo; e0 < hi; e0 += 4) {
    bf16x8 v[4];
    int take[4];
#pragma unroll
    for (int u = 0; u < 4; u++) {
      int e = e0 + u;
      int in = e < hi;
      int p = epk[in ? e : lo];
      int zrow = p & 0x7FFFF;           // always a valid row inside U buffer
      v[u] = *(const bf16x8*)(Zc + (size_t)zrow * HID + t16 * 8);
      take[u] = in && ((p >> 19) == half);
    }
#pragma unroll
    for (int u = 0; u < 4; u++) {
      if (take[u]) {
#pragma unroll
        for (int z = 0; z < 8; z++) acc[z] += (float)v[u][z];
      }
    }
  }

  bf16x8 o;
#pragma unroll
  for (int z = 0; z < 8; z++) o[z] = (__bf16)acc[z];
  *(bf16x8*)(msgb + (size_t)d * HID + t16 * 8) = o;
}

// ---------------------------------------------------------------------------
// gemm_gather: per-relation compacted pass. Zc[base+row] = x[srcOf[base+row]]
//   @ W_rel. 512 threads, 256x128 tile, BK=32, counted-vmcnt (R18 schedule),
//   XCD remap. blockIdx.x = rel (0..3), blockIdx.y = 256-row tile; blocks
//   past cnt exit early. Gather indices loaded once per block.
// ---------------------------------------------------------------------------
__global__ __launch_bounds__(512, 2) void gemm_gather(
    const __bf16* __restrict__ X, const __bf16* __restrict__ Wt4,
    const int* __restrict__ srcOf, const int* __restrict__ Pf,
    __bf16* __restrict__ Zc, int N) {
  constexpr int K = 128, NS = 4;
  __shared__ __bf16 As[2][256][32];
  __shared__ __bf16 Bs[2][128][32];

  const int tid = threadIdx.x;
  int colt, mrow;
  {
    const int gx = gridDim.x;
    const int nb = gx * gridDim.y;
    const int id = blockIdx.x + blockIdx.y * gx;
    const int q = nb >> 3, r8 = nb & 7;
    const int xcd = id & 7, i = id >> 3;
    const int wk = (xcd < r8) ? (xcd * (q + 1) + i)
                              : (r8 * (q + 1) + (xcd - r8) * q + i);
    colt = wk % gx;
    mrow = wk / gx;
  }
  const int rel = colt;
  const int base = Pf[rel * N];
  const int nxt = Pf[(rel + 1) * N];
  const int cnt = nxt - base;
  const int m0 = mrow * 256;
  if (m0 >= cnt) return;
  const __bf16* Bt = Wt4 + (size_t)rel * K * 128;

  const int w = tid >> 6, lane = tid & 63;
  const int cA0 = w * 128 + lane;
  const int rA0 = cA0 >> 2, sA0 = cA0 & 3;
  const int cA1 = cA0 + 64;
  const int rA1 = cA1 >> 2, sA1 = cA1 & 3;
  const int cB = w * 64 + lane;
  const int rB = cB >> 2, sB = cB & 3;

  // gathered A row pointers (clamped; loaded once)
  const int src0 = srcOf[min(base + m0 + rA0, nxt - 1)];
  const int src1 = srcOf[min(base + m0 + rA1, nxt - 1)];
  const __bf16* a0 = X + (size_t)src0 * K + sA0 * 8;
  const __bf16* a1 = X + (size_t)src1 * K + sA1 * 8;

  auto stage_step = [&](int b, int ks) {
    const __bf16* g = Bt + (size_t)rB * K + ks * 32 + sB * 8;
    __builtin_amdgcn_global_load_lds(
        (const __attribute__((address_space(1))) void*)g,
        (__attribute__((address_space(3))) void*)(&Bs[b][0][0] + (size_t)w * 512),
        16, 0, 0);
    __builtin_amdgcn_global_load_lds(
        (const __attribute__((address_space(1))) void*)(a0 + ks * 32),
        (__attribute__((address_space(3))) void*)(&As[b][0][0] + (size_t)(w * 2 + 0) * 512),
        16, 0, 0);
    __builtin_amdgcn_global_load_lds(
        (const __attribute__((address_space(1))) void*)(a1 + ks * 32),
        (__attribute__((address_space(3))) void*)(&As[b][0][0] + (size_t)(w * 2 + 1) * 512),
        16, 0, 0);
  };

  const int ml = lane & 15, q2 = lane >> 4;
  const int wr = (w >> 1) * 64, wc = (w & 1) * 64;

  f32x4 acc[4][4];
#pragma unroll
  for (int i = 0; i < 4; i++)
#pragma unroll
    for (int j = 0; j < 4; j++)
#pragma unroll
      for (int r = 0; r < 4; r++) acc[i][j][r] = 0.f;

  stage_step(0, 0);
  stage_step(1, 1);

#pragma unroll
  for (int ks = 0; ks < NS; ks++) {
    const int cur = ks & 1;
    if (ks + 1 < NS) asm volatile("s_waitcnt vmcnt(3)" ::: "memory");
    else             asm volatile("s_waitcnt vmcnt(0)" ::: "memory");
    asm volatile("s_barrier" ::: "memory");

    bf16x8 af[4], bfr[4];
#pragma unroll
    for (int i = 0; i < 4; i++)
      af[i] = *(const bf16x8*)(&As[cur][wr + i * 16 + ml][q2 * 8]);
#pragma unroll
    for (int j = 0; j < 4; j++)
      bfr[j] = *(const bf16x8*)(&Bs[cur][wc + j * 16 + ml][q2 * 8]);
#pragma unroll
    for (int i = 0; i < 4; i++)
#pragma unroll
      for (int j = 0; j < 4; j++)
        acc[i][j] = __builtin_amdgcn_mfma_f32_16x16x32_bf16(af[i], bfr[j],
                                                            acc[i][j], 0, 0, 0);

    asm volatile("s_barrier" ::: "memory");
    if (ks + 2 < NS) stage_step(cur, ks + 2);
  }

#pragma unroll
  for (int i = 0; i < 4; i++) {
#pragma unroll
    for (int r = 0; r < 4; r++) {
      int lrow = m0 + wr + i * 16 + q2 * 4 + r;
      if (lrow >= cnt) continue;
#pragma unroll
      for (int j = 0; j < 4; j++) {
        int col = wc + j * 16 + ml;
        Zc[(size_t)(base + lrow) * HID + col] = (__bf16)acc[i][j][r];
      }
    }
  }
}

// ---------------------------------------------------------------------------
// DMA-staged bf16 MFMA GEMM (R18/R20-proven): 512 threads, 256x128, BK=32,
// 2 buffers, counted-vmcnt, XCD-chunked bijective block remap.
// ---------------------------------------------------------------------------
template <int K, int K0, int MINW>
__global__ __launch_bounds__(512, MINW) void gemm_lds(
    const __bf16* __restrict__ A0, const __bf16* __restrict__ A1,
    const __bf16* __restrict__ Bt, const float* __restrict__ bias,
    __bf16* __restrict__ Cb, float* __restrict__ Cf,
    int M, int Nc, int act) {
  constexpr int NS = K / 32;
  constexpr int NS0 = K0 / 32;
  constexpr int K1 = (K - K0) > 0 ? (K - K0) : 1;
  __shared__ __bf16 As[2][256][32];
  __shared__ __bf16 Bs[2][128][32];

  const int tid = threadIdx.x;
  int colt, mrow;
  {
    const int gx = gridDim.x;
    const int nb = gx * gridDim.y;
    const int id = blockIdx.x + blockIdx.y * gx;
    const int q = nb >> 3, r8 = nb & 7;
    const int xcd = id & 7, i = id >> 3;
    const int wk = (xcd < r8) ? (xcd * (q + 1) + i)
                              : (r8 * (q + 1) + (xcd - r8) * q + i);
    colt = wk % gx;
    mrow = wk / gx;
  }
  const int m0 = mrow * 256;
  const int bn0 = colt * 128;

  const int w = tid >> 6;
  const int lane = tid & 63;

  const int cA0 = w * 128 + lane;
  const int rA0 = cA0 >> 2, sA0 = cA0 & 3;
  const int cA1 = cA0 + 64;
  const int rA1 = cA1 >> 2, sA1 = cA1 & 3;
  const int cB = w * 64 + lane;
  const int rB = cB >> 2, sB = cB & 3;

  auto stage_step = [&](int b, int ks) {
    {
      const __bf16* g = Bt + (size_t)(bn0 + rB) * K + ks * 32 + sB * 8;
      __builtin_amdgcn_global_load_lds(
          (const __attribute__((address_space(1))) void*)g,
          (__attribute__((address_space(3))) void*)(&Bs[b][0][0] + (size_t)w * 512),
          16, 0, 0);
    }
    if (ks < NS0) {
      const __bf16* g0 = A0 + (size_t)(m0 + rA0) * K0 + ks * 32 + sA0 * 8;
      __builtin_amdgcn_global_load_lds(
          (const __attribute__((address_space(1))) void*)g0,
          (__attribute__((address_space(3))) void*)(&As[b][0][0] + (size_t)(w * 2 + 0) * 512),
          16, 0, 0);
      const __bf16* g1 = A0 + (size_t)(m0 + rA1) * K0 + ks * 32 + sA1 * 8;
      __builtin_amdgcn_global_load_lds(
          (const __attribute__((address_space(1))) void*)g1,
          (__attribute__((address_space(3))) void*)(&As[b][0][0] + (size_t)(w * 2 + 1) * 512),
          16, 0, 0);
    } else {
      const __bf16* g0 = A1 + (size_t)(m0 + rA0) * K1 + (ks - NS0) * 32 + sA0 * 8;
      __builtin_amdgcn_global_load_lds(
          (const __attribute__((address_space(1))) void*)g0,
          (__attribute__((address_space(3))) void*)(&As[b][0][0] + (size_t)(w * 2 + 0) * 512),
          16, 0, 0);
      const __bf16* g1 = A1 + (size_t)(m0 + rA1) * K1 + (ks - NS0) * 32 + sA1 * 8;
      __builtin_amdgcn_global_load_lds(
          (const __attribute__((address_space(1))) void*)g1,
          (__attribute__((address_space(3))) void*)(&As[b][0][0] + (size_t)(w * 2 + 1) * 512),
          16, 0, 0);
    }
  };

  const int ml = lane & 15, q2 = lane >> 4;
  const int wr = (w >> 1) * 64;
  const int wc = (w & 1) * 64;

  f32x4 acc[4][4];
#pragma unroll
  for (int i = 0; i < 4; i++)
#pragma unroll
    for (int j = 0; j < 4; j++)
#pragma unroll
      for (int r = 0; r < 4; r++) acc[i][j][r] = 0.f;

  stage_step(0, 0);
  if (NS > 1) stage_step(1, 1);

#pragma unroll
  for (int ks = 0; ks < NS; ks++) {
    const int cur = ks & 1;
    if (ks + 1 < NS) asm volatile("s_waitcnt vmcnt(3)" ::: "memory");
    else             asm volatile("s_waitcnt vmcnt(0)" ::: "memory");
    asm volatile("s_barrier" ::: "memory");

    bf16x8 af[4], bfr[4];
#pragma unroll
    for (int i = 0; i < 4; i++)
      af[i] = *(const bf16x8*)(&As[cur][wr + i * 16 + ml][q2 * 8]);
#pragma unroll
    for (int j = 0; j < 4; j++)
      bfr[j] = *(const bf16x8*)(&Bs[cur][wc + j * 16 + ml][q2 * 8]);
#pragma unroll
    for (int i = 0; i < 4; i++)
#pragma unroll
      for (int j = 0; j < 4; j++)
        acc[i][j] = __builtin_amdgcn_mfma_f32_16x16x32_bf16(af[i], bfr[j],
                                                            acc[i][j], 0, 0, 0);

    asm volatile("s_barrier" ::: "memory");
    if (ks + 2 < NS) stage_step(cur, ks + 2);
  }

#pragma unroll
  for (int i = 0; i < 4; i++) {
#pragma unroll
    for (int r = 0; r < 4; r++) {
      int grow = m0 + wr + i * 16 + q2 * 4 + r;
      if (grow >= M) continue;
#pragma unroll
      for (int j = 0; j < 4; j++) {
        int col = bn0 + wc + j * 16 + ml;
        float v = acc[i][j][r];
        if (bias) v += bias[col];
        if (act) v = fast_tanh(v);
        if (Cb) Cb[(size_t)grow * Nc + col] = (__bf16)v;
        if (Cf) Cf[(size_t)grow * Nc + col] = v;
      }
    }
  }
}

extern "C" void kernel_launch(void* const* d_in, const int* in_sizes, int n_in,
                              void* d_out, int out_size, void* d_ws, size_t ws_size,
                              hipStream_t stream) {
  const float* feats  = (const float*)d_in[0];
  const int*   src    = (const int*)d_in[1];
  const int*   dst    = (const int*)d_in[2];
  const int*   etype  = (const int*)d_in[3];
  const float* W_in   = (const float*)d_in[4];
  const float* b_in   = (const float*)d_in[5];
  const float* W_rel  = (const float*)d_in[6];
  const float* W_loop = (const float*)d_in[7];
  const float* b_rel  = (const float*)d_in[8];
  const float* W_u1   = (const float*)d_in[9];
  const float* b_u1   = (const float*)d_in[10];
  const float* W_u2   = (const float*)d_in[11];
  const float* b_u2   = (const float*)d_in[12];

  const int E = in_sizes[1];
  const int N = in_sizes[0] / 64;
  const int TS = HID * HID;

  // --- workspace layout (~220 MB + 10 MB prep tables) ---
  __bf16* xb0  = (__bf16*)d_ws;                       // N*128
  __bf16* xb1  = xb0 + (size_t)N * HID;               // N*128
  __bf16* msgb = xb1 + (size_t)N * HID;               // N*128
  __bf16* U    = msgb + (size_t)N * HID;              // N*640 (Zc | mid | featsb)
  __bf16* Z    = U;
  __bf16* mid  = U;
  __bf16* featsb = U;
  __bf16* wt_in = U + (size_t)N * 640;                // [128][64]
  __bf16* wt_z0 = wt_in + 128 * 64;                   // [10][4][128][128]
  __bf16* wt_z1 = wt_z0 + (size_t)10 * 4 * TS;        // [10][4][128][128]
  __bf16* wt_u1 = wt_z1 + (size_t)10 * 4 * TS;        // [10][256][256]
  __bf16* wt_u2 = wt_u1 + (size_t)10 * 256 * 256;     // [10][128][384]
  int* rowCnt   = (int*)(wt_u2 + (size_t)10 * 128 * 384); // N
  int* rowStart = rowCnt + N;                         // N+1
  int* rowCur   = rowStart + N + 1;                   // N
  int* epk      = rowCur + N;                         // E
  int* thrPre   = epk + E;                            // 256*256
  int* blkSum   = thrPre + 256 * 256;                 // 256
  int* blkOff   = blkSum + 256;                       // 256
  int* F0       = blkOff + 256;                       // 4N
  int* F1       = F0 + 4 * N;                         // 4N
  int* P0       = F1 + 4 * N;                         // 4N+1
  int* P1       = P0 + 4 * N + 1;                     // 4N+1
  int* S0       = P1 + 4 * N + 1;                     // 4N (srcOf half 0)
  int* S1       = S0 + 4 * N;                         // 4N

  // --- weight transpose+convert ---
  k_transpose<<<dim3(4, 2, 1), dim3(32, 8), 0, stream>>>(W_in, wt_in, 64, 128,
                                                         1, 1, 0, 1, 1, 0);
  k_transpose<<<dim3(4, 4, 40), dim3(32, 8), 0, stream>>>(W_rel, wt_z0, 128, 128,
                                                          4, 8, 0, 4, 4, 0);
  k_transpose<<<dim3(4, 4, 40), dim3(32, 8), 0, stream>>>(W_rel, wt_z1, 128, 128,
                                                          4, 8, 4, 4, 4, 0);
  k_transpose<<<dim3(8, 8, 10), dim3(32, 8), 0, stream>>>(W_u1, wt_u1, 256, 256,
                                                          1, 1, 0, 1, 1, 0);
  k_fold_wu1<<<dim3(8, 10), dim3(256), 0, stream>>>(W_u1, W_loop, wt_u1);
  k_transpose<<<dim3(4, 12, 10), dim3(32, 8), 0, stream>>>(W_u2, wt_u2, 384, 128,
                                                           1, 1, 0, 1, 1, 0);
  k_cvt<<<(N * 64 / 4 + 255) / 256, 256, 0, stream>>>(feats, featsb, N * 64 / 4);

  // --- dst-CSR + compaction tables ---
  k_zero<<<128, 256, 0, stream>>>(rowCnt, N);
  k_zero<<<256, 256, 0, stream>>>(F0, 4 * N);
  k_zero<<<256, 256, 0, stream>>>(F1, 4 * N);
  k_hist_row<<<(E + 255) / 256, 256, 0, stream>>>(dst, E, rowCnt);
  k_flag<<<(E + 255) / 256, 256, 0, stream>>>(etype, src, E, N, F0, F1);
  // CSR row scan
  k_scan_part<<<256, 256, 0, stream>>>(rowCnt, N, thrPre, blkSum);
  k_scan_mid<<<1, 256, 0, stream>>>(blkSum, 256, N, blkOff, rowStart);
  k_scan_fin<<<256, 256, 0, stream>>>(rowCnt, N, thrPre, blkOff, rowStart, rowCur);
  // flag scans (rank tables)
  k_scan_part<<<256, 256, 0, stream>>>(F0, 4 * N, thrPre, blkSum);
  k_scan_mid<<<1, 256, 0, stream>>>(blkSum, 256, 4 * N, blkOff, P0);
  k_scan_fin<<<256, 256, 0, stream>>>(F0, 4 * N, thrPre, blkOff, P0, nullptr);
  k_scan_part<<<256, 256, 0, stream>>>(F1, 4 * N, thrPre, blkSum);
  k_scan_mid<<<1, 256, 0, stream>>>(blkSum, 256, 4 * N, blkOff, P1);
  k_scan_fin<<<256, 256, 0, stream>>>(F1, 4 * N, thrPre, blkOff, P1, nullptr);
  // gather tables + edge placement
  k_srcof<<<(4 * N + 255) / 256, 256, 0, stream>>>(F0, P0, 4 * N, N, S0);
  k_srcof<<<(4 * N + 255) / 256, 256, 0, stream>>>(F1, P1, 4 * N, N, S1);
  k_place_row<<<(E + 255) / 256, 256, 0, stream>>>(etype, src, dst, P0, P1,
                                                   rowCur, epk, E, N);

  const dim3 blk(512);
  const int gm = (N + 255) / 256;
  const dim3 gseg((N + 15) / 16);

  // input projection: x0 = tanh(featsb @ W_in + b_in)
  gemm_lds<64, 64, 2><<<dim3(1, gm), blk, 0, stream>>>(
      featsb, featsb, wt_in, b_in, xb0, nullptr, N, HID, 1);

  for (int l = 0; l < NL; l++) {
    const __bf16* xin = (l & 1) ? xb1 : xb0;
    __bf16* xout = (l & 1) ? xb0 : xb1;

    // pass 0 (compacted): Zc[P0-rows] = x[srcOf] @ W_r, r=0..3
    gemm_gather<<<dim3(4, gm), blk, 0, stream>>>(
        xin, wt_z0 + (size_t)l * 4 * TS, S0, P0, Z, N);
    // seg0: msg = b_rel + sum(half-0 edges) Zc[zrow]
    seg_sum<<<gseg, dim3(256), 0, stream>>>(Z, rowStart, epk,
                                            b_rel + (size_t)l * HID,
                                            msgb, N, 0);
    // pass 1 (compacted): rels 4..7
    gemm_gather<<<dim3(4, gm), blk, 0, stream>>>(
        xin, wt_z1 + (size_t)l * 4 * TS, S1, P1, Z, N);
    // seg1: msg += sum(half-1 edges)
    seg_sum<<<gseg, dim3(256), 0, stream>>>(Z, rowStart, epk, nullptr,
                                            msgb, N, 1);

    // mid = tanh([x | msg] @ Wu1_eff[l] + b_u1[l])   (mid aliases Z)
    gemm_lds<256, 128, 2><<<dim3(2, gm), blk, 0, stream>>>(
        xin, msgb, wt_u1 + (size_t)l * 256 * 256, b_u1 + (size_t)l * 256,
        mid, nullptr, N, 256, 1);

    // x' = tanh([x | mid] @ W_u2[l] + b_u2[l]); last layer -> f32 d_out
    gemm_lds<384, 128, 2><<<dim3(1, gm), blk, 0, stream>>>(
        xin, mid, wt_u2 + (size_t)l * HID * 384, b_u2 + (size_t)l * HID,
        (l == NL - 1) ? nullptr : xout,
        (l == NL - 1) ? (float*)d_out : nullptr,
        N, HID, 1);
  }
}

// Round 14
// 1920.251 us; speedup vs baseline: 1.4086x; 1.1947x over previous
//
#include <hip/hip_runtime.h>
#include <cstddef>

// ---------------------------------------------------------------------------
// RelGraphConv GNN, 10 layers. Round 22: merged 8-rel gather + single seg,
//   128-tile GEMM for U2/proj.
//   R21 budget: GEMM wall time ~= #K-steps x 6.8 us (latency-tail per step,
//   not BW). Levers: (a) U2/proj ran 391 blocks = 1.5/CU (half machine idle)
//   -> new gemm_lds128 (128x128 tile, 256 thr, same counted-vmcnt schedule,
//   vmcnt(4)) gives 782 blocks = 3/CU; (b) pass0+pass1+seg0+seg1 merge into
//   ONE 8-relation gather GEMM + ONE seg (single F/P/S over 8N; epk = 19-bit
//   compact zrow, no half flag) -> kills msgb round-trip (-51 MB/layer),
//   merges latency tails, seg edge loop 2x denser.
//   Zc rows ~= 8N(1-e^-.75) ~= 423K < 500K cap (U = N*640 elems).
// Keeps: R18/R20 512-thr GEMM for U1, XCD remap, W_loop fold, fast_tanh,
//        parallel scan, 4-wide seg unroll.
// N=100000, E=600000, F=64, H=128, R=8.
// ---------------------------------------------------------------------------

#define HID 128
#define NREL 8
#define NL 10

typedef __attribute__((ext_vector_type(8))) __bf16 bf16x8;
typedef __attribute__((ext_vector_type(4))) float f32x4;

__device__ __forceinline__ float fast_tanh(float x) {
  float cx = fminf(fmaxf(x, -10.f), 10.f);
  float z = exp2f(cx * 2.8853900817779268f);
  return (z - 1.f) * __builtin_amdgcn_rcpf(z + 1.f);
}

// --- batched transpose + f32->bf16: tile z: W[zi][K][Nc] -> Wt[zo][Nc][K] ---
__global__ __launch_bounds__(256) void k_transpose(const float* __restrict__ W,
                                                   __bf16* __restrict__ Wt,
                                                   int K, int Nc,
                                                   int inDiv, int inScale, int inOff,
                                                   int outDiv, int outScale, int outOff) {
  __shared__ float t[32][33];
  int z = blockIdx.z;
  int zi = (z / inDiv) * inScale + (z % inDiv) + inOff;
  int zo = (z / outDiv) * outScale + (z % outDiv) + outOff;
  const float* Wz = W + (size_t)zi * K * Nc;
  __bf16* Wtz = Wt + (size_t)zo * K * Nc;
  int n0 = blockIdx.x * 32, k0 = blockIdx.y * 32;
#pragma unroll
  for (int i = 0; i < 4; i++) {
    int k = k0 + threadIdx.y + i * 8;
    int n = n0 + threadIdx.x;
    t[threadIdx.y + i * 8][threadIdx.x] = Wz[(size_t)k * Nc + n];
  }
  __syncthreads();
#pragma unroll
  for (int i = 0; i < 4; i++) {
    int n = n0 + threadIdx.y + i * 8;
    int k = k0 + threadIdx.x;
    Wtz[(size_t)n * K + k] = (__bf16)t[threadIdx.x][threadIdx.y + i * 8];
  }
}

// --- fold W_loop into wt_u1 (k<128 rows) ---
__global__ __launch_bounds__(256) void k_fold_wu1(const float* __restrict__ Wu1,
                                                  const float* __restrict__ Wloop,
                                                  __bf16* __restrict__ wt) {
  int l = blockIdx.y;
  int n0 = blockIdx.x * 32;
  const float* wu1 = Wu1 + (size_t)l * 256 * 256;
  const float* wl = Wloop + (size_t)l * 128 * 128;
  __bf16* wtl = wt + (size_t)l * 256 * 256;
  __shared__ float bot[128][33];
  for (int t = threadIdx.x; t < 128 * 32; t += 256) {
    int j = t >> 5, c = t & 31;
    bot[j][c] = wu1[(size_t)(128 + j) * 256 + n0 + c];
  }
  __syncthreads();
  int k = threadIdx.x & 127;
  int half = threadIdx.x >> 7;
  float acc[16];
#pragma unroll
  for (int c = 0; c < 16; c++) acc[c] = 0.f;
  for (int j = 0; j < 128; j++) {
    float w = wl[(size_t)k * 128 + j];
#pragma unroll
    for (int c = 0; c < 16; c++) acc[c] += w * bot[j][half * 16 + c];
  }
#pragma unroll
  for (int c = 0; c < 16; c++) {
    int n = n0 + half * 16 + c;
    wtl[(size_t)n * 256 + k] = (__bf16)(wu1[(size_t)k * 256 + n] + acc[c]);
  }
}

// --- f32 -> bf16 elementwise (n4 = count/4) ---
__global__ __launch_bounds__(256) void k_cvt(const float* __restrict__ x,
                                             __bf16* __restrict__ y, int n4) {
  int i = blockIdx.x * 256 + threadIdx.x;
  if (i < n4) {
    float4 f = ((const float4*)x)[i];
    __bf16 o[4] = {(__bf16)f.x, (__bf16)f.y, (__bf16)f.z, (__bf16)f.w};
    *(uint2*)(y + (size_t)i * 4) = *(uint2*)o;
  }
}

// ===================== prep kernels (once per launch) =======================
__global__ __launch_bounds__(256) void k_zero(int* __restrict__ p, int n) {
  for (int i = blockIdx.x * 256 + threadIdx.x; i < n; i += gridDim.x * 256) p[i] = 0;
}

__global__ __launch_bounds__(256) void k_hist_row(const int* __restrict__ dst,
                                                  int E, int* __restrict__ rowCnt) {
  int e = blockIdx.x * 256 + threadIdx.x;
  if (e < E) atomicAdd(&rowCnt[dst[e]], 1);
}

// flag active (rel, src) pairs over all 8 relations
__global__ __launch_bounds__(256) void k_flag(const int* __restrict__ et,
                                              const int* __restrict__ src,
                                              int E, int N, int* __restrict__ F) {
  int e = blockIdx.x * 256 + threadIdx.x;
  if (e < E) F[(size_t)et[e] * N + src[e]] = 1;
}

// scatter node ids to compact-row table
__global__ __launch_bounds__(256) void k_srcof(const int* __restrict__ F,
                                               const int* __restrict__ P,
                                               int n, int N, int* __restrict__ srcOf) {
  int i = blockIdx.x * 256 + threadIdx.x;
  if (i < n && F[i]) srcOf[P[i]] = i % N;
}

// --- hierarchical prefix scan over cnt[0..nb) -------------------------------
__global__ __launch_bounds__(256) void k_scan_part(const int* __restrict__ cntArr,
                                                   int nb, int* __restrict__ thrPre,
                                                   int* __restrict__ blkSum) {
  __shared__ int sdata[256];
  int tid = threadIdx.x;
  int gtid = blockIdx.x * 256 + tid;
  int tot = gridDim.x * 256;
  int chunk = (nb + tot - 1) / tot;
  int lo = gtid * chunk, hi = min(nb, lo + chunk);
  int s = 0;
  for (int i = lo; i < hi; i++) s += cntArr[i];
  sdata[tid] = s;
  __syncthreads();
#pragma unroll
  for (int off = 1; off < 256; off <<= 1) {
    int t = (tid >= off) ? sdata[tid - off] : 0;
    __syncthreads();
    sdata[tid] += t;
    __syncthreads();
  }
  thrPre[gtid] = sdata[tid] - s;
  if (tid == 255) blkSum[blockIdx.x] = sdata[255];
}

__global__ __launch_bounds__(256) void k_scan_mid(const int* __restrict__ blkSum,
                                                  int nblk, int nb,
                                                  int* __restrict__ blkOff,
                                                  int* __restrict__ pre) {
  __shared__ int part[256];
  int tid = threadIdx.x;
  part[tid] = (tid < nblk) ? blkSum[tid] : 0;
  __syncthreads();
  if (tid == 0) {
    int a = 0;
    for (int i = 0; i < nblk; i++) { int v = part[i]; part[i] = a; a += v; }
    pre[nb] = a;
  }
  __syncthreads();
  if (tid < nblk) blkOff[tid] = part[tid];
}

__global__ __launch_bounds__(256) void k_scan_fin(const int* __restrict__ cntArr,
                                                  int nb,
                                                  const int* __restrict__ thrPre,
                                                  const int* __restrict__ blkOff,
                                                  int* __restrict__ pre,
                                                  int* __restrict__ cur) {
  int tid = threadIdx.x;
  int gtid = blockIdx.x * 256 + tid;
  int tot = gridDim.x * 256;
  int chunk = (nb + tot - 1) / tot;
  int lo = gtid * chunk, hi = min(nb, lo + chunk);
  int run = blkOff[blockIdx.x] + thrPre[gtid];
  for (int i = lo; i < hi; i++) {
    pre[i] = run;
    if (cur) cur[i] = run;
    run += cntArr[i];
  }
}

// epk = compact zrow (all relations in one table)
__global__ __launch_bounds__(256) void k_place_row(const int* __restrict__ et,
                                                   const int* __restrict__ src,
                                                   const int* __restrict__ dst,
                                                   const int* __restrict__ P,
                                                   int* __restrict__ rowCur,
                                                   int* __restrict__ epk, int E, int N) {
  int e = blockIdx.x * 256 + threadIdx.x;
  if (e < E) {
    int p = atomicAdd(&rowCur[dst[e]], 1);
    epk[p] = P[(size_t)et[e] * N + src[e]];
  }
}

// ========================= CSR segment-sum kernel ===========================
// Single pass over ALL edges: msg[d] = b_rel + sum_e Zc[epk[e]].
// 16 lanes per dst row; 4-wide edge unroll (all loads issue before adds).
__global__ __launch_bounds__(256) void seg_sum(
    const __bf16* __restrict__ Zc, const int* __restrict__ rowStart,
    const int* __restrict__ epk, const float* __restrict__ b_rel_l,
    __bf16* __restrict__ msgb, int N) {
  int t16 = threadIdx.x & 15;
  int d = blockIdx.x * 16 + (threadIdx.x >> 4);
  if (d >= N) return;

  float acc[8];
#pragma unroll
  for (int z = 0; z < 8; z++) acc[z] = b_rel_l[t16 * 8 + z];

  const int lo = rowStart[d], hi = rowStart[d + 1];
  for (int e0 = lo; e0 < hi; e0 += 4) {
    bf16x8 v[4];
    int take[4];
#pragma unroll
    for (int u = 0; u < 4; u++) {
      int e = e0 + u;
      int in = e < hi;
      int zrow = epk[in ? e : lo];
      v[u] = *(const bf16x8*)(Zc + (size_t)zrow * HID + t16 * 8);
      take[u] = in;
    }
#pragma unroll
    for (int u = 0; u < 4; u++) {
      if (take[u]) {
#pragma unroll
        for (int z = 0; z < 8; z++) acc[z] += (float)v[u][z];
      }
    }
  }

  bf16x8 o;
#pragma unroll
  for (int z = 0; z < 8; z++) o[z] = (__bf16)acc[z];
  *(bf16x8*)(msgb + (size_t)d * HID + t16 * 8) = o;
}

// ---------------------------------------------------------------------------
// gemm_gather: 8-relation compacted pass. Zc[base+row] = x[srcOf[base+row]]
//   @ W_rel. 512 threads, 256x128 tile, BK=32, counted-vmcnt, XCD remap.
//   blockIdx.x = rel (0..7); blocks past cnt exit early.
// ---------------------------------------------------------------------------
__global__ __launch_bounds__(512, 2) void gemm_gather(
    const __bf16* __restrict__ X, const __bf16* __restrict__ Wt8,
    const int* __restrict__ srcOf, const int* __restrict__ Pf,
    __bf16* __restrict__ Zc, int N) {
  constexpr int K = 128, NS = 4;
  __shared__ __bf16 As[2][256][32];
  __shared__ __bf16 Bs[2][128][32];

  const int tid = threadIdx.x;
  int colt, mrow;
  {
    const int gx = gridDim.x;
    const int nb = gx * gridDim.y;
    const int id = blockIdx.x + blockIdx.y * gx;
    const int q = nb >> 3, r8 = nb & 7;
    const int xcd = id & 7, i = id >> 3;
    const int wk = (xcd < r8) ? (xcd * (q + 1) + i)
                              : (r8 * (q + 1) + (xcd - r8) * q + i);
    colt = wk % gx;
    mrow = wk / gx;
  }
  const int rel = colt;
  const int base = Pf[(size_t)rel * N];
  const int nxt = Pf[(size_t)(rel + 1) * N];
  const int cnt = nxt - base;
  const int m0 = mrow * 256;
  if (m0 >= cnt) return;
  const __bf16* Bt = Wt8 + (size_t)rel * K * 128;

  const int w = tid >> 6, lane = tid & 63;
  const int cA0 = w * 128 + lane;
  const int rA0 = cA0 >> 2, sA0 = cA0 & 3;
  const int cA1 = cA0 + 64;
  const int rA1 = cA1 >> 2, sA1 = cA1 & 3;
  const int cB = w * 64 + lane;
  const int rB = cB >> 2, sB = cB & 3;

  // gathered A row pointers (clamped; loaded once)
  const int src0 = srcOf[min(base + m0 + rA0, nxt - 1)];
  const int src1 = srcOf[min(base + m0 + rA1, nxt - 1)];
  const __bf16* a0 = X + (size_t)src0 * K + sA0 * 8;
  const __bf16* a1 = X + (size_t)src1 * K + sA1 * 8;

  auto stage_step = [&](int b, int ks) {
    const __bf16* g = Bt + (size_t)rB * K + ks * 32 + sB * 8;
    __builtin_amdgcn_global_load_lds(
        (const __attribute__((address_space(1))) void*)g,
        (__attribute__((address_space(3))) void*)(&Bs[b][0][0] + (size_t)w * 512),
        16, 0, 0);
    __builtin_amdgcn_global_load_lds(
        (const __attribute__((address_space(1))) void*)(a0 + ks * 32),
        (__attribute__((address_space(3))) void*)(&As[b][0][0] + (size_t)(w * 2 + 0) * 512),
        16, 0, 0);
    __builtin_amdgcn_global_load_lds(
        (const __attribute__((address_space(1))) void*)(a1 + ks * 32),
        (__attribute__((address_space(3))) void*)(&As[b][0][0] + (size_t)(w * 2 + 1) * 512),
        16, 0, 0);
  };

  const int ml = lane & 15, q2 = lane >> 4;
  const int wr = (w >> 1) * 64, wc = (w & 1) * 64;

  f32x4 acc[4][4];
#pragma unroll
  for (int i = 0; i < 4; i++)
#pragma unroll
    for (int j = 0; j < 4; j++)
#pragma unroll
      for (int r = 0; r < 4; r++) acc[i][j][r] = 0.f;

  stage_step(0, 0);
  stage_step(1, 1);

#pragma unroll
  for (int ks = 0; ks < NS; ks++) {
    const int cur = ks & 1;
    if (ks + 1 < NS) asm volatile("s_waitcnt vmcnt(3)" ::: "memory");
    else             asm volatile("s_waitcnt vmcnt(0)" ::: "memory");
    asm volatile("s_barrier" ::: "memory");

    bf16x8 af[4], bfr[4];
#pragma unroll
    for (int i = 0; i < 4; i++)
      af[i] = *(const bf16x8*)(&As[cur][wr + i * 16 + ml][q2 * 8]);
#pragma unroll
    for (int j = 0; j < 4; j++)
      bfr[j] = *(const bf16x8*)(&Bs[cur][wc + j * 16 + ml][q2 * 8]);
#pragma unroll
    for (int i = 0; i < 4; i++)
#pragma unroll
      for (int j = 0; j < 4; j++)
        acc[i][j] = __builtin_amdgcn_mfma_f32_16x16x32_bf16(af[i], bfr[j],
                                                            acc[i][j], 0, 0, 0);

    asm volatile("s_barrier" ::: "memory");
    if (ks + 2 < NS) stage_step(cur, ks + 2);
  }

#pragma unroll
  for (int i = 0; i < 4; i++) {
#pragma unroll
    for (int r = 0; r < 4; r++) {
      int lrow = m0 + wr + i * 16 + q2 * 4 + r;
      if (lrow >= cnt) continue;
#pragma unroll
      for (int j = 0; j < 4; j++) {
        int col = wc + j * 16 + ml;
        Zc[(size_t)(base + lrow) * HID + col] = (__bf16)acc[i][j][r];
      }
    }
  }
}

// ---------------------------------------------------------------------------
// gemm_lds (512 thr, 256x128, BK=32, counted vmcnt, XCD remap) — for U1.
// ---------------------------------------------------------------------------
template <int K, int K0, int MINW>
__global__ __launch_bounds__(512, MINW) void gemm_lds(
    const __bf16* __restrict__ A0, const __bf16* __restrict__ A1,
    const __bf16* __restrict__ Bt, const float* __restrict__ bias,
    __bf16* __restrict__ Cb, float* __restrict__ Cf,
    int M, int Nc, int act) {
  constexpr int NS = K / 32;
  constexpr int NS0 = K0 / 32;
  constexpr int K1 = (K - K0) > 0 ? (K - K0) : 1;
  __shared__ __bf16 As[2][256][32];
  __shared__ __bf16 Bs[2][128][32];

  const int tid = threadIdx.x;
  int colt, mrow;
  {
    const int gx = gridDim.x;
    const int nb = gx * gridDim.y;
    const int id = blockIdx.x + blockIdx.y * gx;
    const int q = nb >> 3, r8 = nb & 7;
    const int xcd = id & 7, i = id >> 3;
    const int wk = (xcd < r8) ? (xcd * (q + 1) + i)
                              : (r8 * (q + 1) + (xcd - r8) * q + i);
    colt = wk % gx;
    mrow = wk / gx;
  }
  const int m0 = mrow * 256;
  const int bn0 = colt * 128;

  const int w = tid >> 6;
  const int lane = tid & 63;

  const int cA0 = w * 128 + lane;
  const int rA0 = cA0 >> 2, sA0 = cA0 & 3;
  const int cA1 = cA0 + 64;
  const int rA1 = cA1 >> 2, sA1 = cA1 & 3;
  const int cB = w * 64 + lane;
  const int rB = cB >> 2, sB = cB & 3;

  auto stage_step = [&](int b, int ks) {
    {
      const __bf16* g = Bt + (size_t)(bn0 + rB) * K + ks * 32 + sB * 8;
      __builtin_amdgcn_global_load_lds(
          (const __attribute__((address_space(1))) void*)g,
          (__attribute__((address_space(3))) void*)(&Bs[b][0][0] + (size_t)w * 512),
          16, 0, 0);
    }
    if (ks < NS0) {
      const __bf16* g0 = A0 + (size_t)(m0 + rA0) * K0 + ks * 32 + sA0 * 8;
      __builtin_amdgcn_global_load_lds(
          (const __attribute__((address_space(1))) void*)g0,
          (__attribute__((address_space(3))) void*)(&As[b][0][0] + (size_t)(w * 2 + 0) * 512),
          16, 0, 0);
      const __bf16* g1 = A0 + (size_t)(m0 + rA1) * K0 + ks * 32 + sA1 * 8;
      __builtin_amdgcn_global_load_lds(
          (const __attribute__((address_space(1))) void*)g1,
          (__attribute__((address_space(3))) void*)(&As[b][0][0] + (size_t)(w * 2 + 1) * 512),
          16, 0, 0);
    } else {
      const __bf16* g0 = A1 + (size_t)(m0 + rA0) * K1 + (ks - NS0) * 32 + sA0 * 8;
      __builtin_amdgcn_global_load_lds(
          (const __attribute__((address_space(1))) void*)g0,
          (__attribute__((address_space(3))) void*)(&As[b][0][0] + (size_t)(w * 2 + 0) * 512),
          16, 0, 0);
      const __bf16* g1 = A1 + (size_t)(m0 + rA1) * K1 + (ks - NS0) * 32 + sA1 * 8;
      __builtin_amdgcn_global_load_lds(
          (const __attribute__((address_space(1))) void*)g1,
          (__attribute__((address_space(3))) void*)(&As[b][0][0] + (size_t)(w * 2 + 1) * 512),
          16, 0, 0);
    }
  };

  const int ml = lane & 15, q2 = lane >> 4;
  const int wr = (w >> 1) * 64;
  const int wc = (w & 1) * 64;

  f32x4 acc[4][4];
#pragma unroll
  for (int i = 0; i < 4; i++)
#pragma unroll
    for (int j = 0; j < 4; j++)
#pragma unroll
      for (int r = 0; r < 4; r++) acc[i][j][r] = 0.f;

  stage_step(0, 0);
  if (NS > 1) stage_step(1, 1);

#pragma unroll
  for (int ks = 0; ks < NS; ks++) {
    const int cur = ks & 1;
    if (ks + 1 < NS) asm volatile("s_waitcnt vmcnt(3)" ::: "memory");
    else             asm volatile("s_waitcnt vmcnt(0)" ::: "memory");
    asm volatile("s_barrier" ::: "memory");

    bf16x8 af[4], bfr[4];
#pragma unroll
    for (int i = 0; i < 4; i++)
      af[i] = *(const bf16x8*)(&As[cur][wr + i * 16 + ml][q2 * 8]);
#pragma unroll
    for (int j = 0; j < 4; j++)
      bfr[j] = *(const bf16x8*)(&Bs[cur][wc + j * 16 + ml][q2 * 8]);
#pragma unroll
    for (int i = 0; i < 4; i++)
#pragma unroll
      for (int j = 0; j < 4; j++)
        acc[i][j] = __builtin_amdgcn_mfma_f32_16x16x32_bf16(af[i], bfr[j],
                                                            acc[i][j], 0, 0, 0);

    asm volatile("s_barrier" ::: "memory");
    if (ks + 2 < NS) stage_step(cur, ks + 2);
  }

#pragma unroll
  for (int i = 0; i < 4; i++) {
#pragma unroll
    for (int r = 0; r < 4; r++) {
      int grow = m0 + wr + i * 16 + q2 * 4 + r;
      if (grow >= M) continue;
#pragma unroll
      for (int j = 0; j < 4; j++) {
        int col = bn0 + wc + j * 16 + ml;
        float v = acc[i][j][r];
        if (bias) v += bias[col];
        if (act) v = fast_tanh(v);
        if (Cb) Cb[(size_t)grow * Nc + col] = (__bf16)v;
        if (Cf) Cf[(size_t)grow * Nc + col] = v;
      }
    }
  }
}

// ---------------------------------------------------------------------------
// gemm_lds128: 256 threads, 128x128 C-tile, BK=32, counted vmcnt, XCD remap.
//   For Nc=128 GEMMs (U2, proj): grid = (1, ceil(M/128)) = 782 blocks = 3/CU
//   (the 512-thr version would launch only 391 = 1.5/CU).
//   Per wave per stage: A 2 insts + B 2 insts = 4 -> steady vmcnt(4).
// ---------------------------------------------------------------------------
template <int K, int K0, int MINW>
__global__ __launch_bounds__(256, MINW) void gemm_lds128(
    const __bf16* __restrict__ A0, const __bf16* __restrict__ A1,
    const __bf16* __restrict__ Bt, const float* __restrict__ bias,
    __bf16* __restrict__ Cb, float* __restrict__ Cf,
    int M, int Nc, int act) {
  constexpr int NS = K / 32;
  constexpr int NS0 = K0 / 32;
  constexpr int K1 = (K - K0) > 0 ? (K - K0) : 1;
  __shared__ __bf16 As[2][128][32];
  __shared__ __bf16 Bs[2][128][32];

  const int tid = threadIdx.x;
  int colt, mrow;
  {
    const int gx = gridDim.x;
    const int nb = gx * gridDim.y;
    const int id = blockIdx.x + blockIdx.y * gx;
    const int q = nb >> 3, r8 = nb & 7;
    const int xcd = id & 7, i = id >> 3;
    const int wk = (xcd < r8) ? (xcd * (q + 1) + i)
                              : (r8 * (q + 1) + (xcd - r8) * q + i);
    colt = wk % gx;
    mrow = wk / gx;
  }
  const int m0 = mrow * 128;
  const int bn0 = colt * 128;

  const int w = tid >> 6;       // 0..3
  const int lane = tid & 63;

  // 128x32 tile = 512 chunks (16B): chunk c -> row c>>2, slot c&3.
  // wave w: c = w*128 + j*64 + lane (j=0,1) -> 2 insts per operand.
  const int c0 = w * 128 + lane;
  const int r0 = c0 >> 2, s0 = c0 & 3;
  const int c1 = c0 + 64;
  const int r1 = c1 >> 2, s1 = c1 & 3;

  auto stage_step = [&](int b, int ks) {
    const __bf16* gB0 = Bt + (size_t)(bn0 + r0) * K + ks * 32 + s0 * 8;
    __builtin_amdgcn_global_load_lds(
        (const __attribute__((address_space(1))) void*)gB0,
        (__attribute__((address_space(3))) void*)(&Bs[b][0][0] + (size_t)(w * 2 + 0) * 512),
        16, 0, 0);
    const __bf16* gB1 = Bt + (size_t)(bn0 + r1) * K + ks * 32 + s1 * 8;
    __builtin_amdgcn_global_load_lds(
        (const __attribute__((address_space(1))) void*)gB1,
        (__attribute__((address_space(3))) void*)(&Bs[b][0][0] + (size_t)(w * 2 + 1) * 512),
        16, 0, 0);
    if (ks < NS0) {
      const __bf16* g0 = A0 + (size_t)(m0 + r0) * K0 + ks * 32 + s0 * 8;
      __builtin_amdgcn_global_load_lds(
          (const __attribute__((address_space(1))) void*)g0,
          (__attribute__((address_space(3))) void*)(&As[b][0][0] + (size_t)(w * 2 + 0) * 512),
          16, 0, 0);
      const __bf16* g1 = A0 + (size_t)(m0 + r1) * K0 + ks * 32 + s1 * 8;
      __builtin_amdgcn_global_load_lds(
          (const __attribute__((address_space(1))) void*)g1,
          (__attribute__((address_space(3))) void*)(&As[b][0][0] + (size_t)(w * 2 + 1) * 512),
          16, 0, 0);
    } else {
      const __bf16* g0 = A1 + (size_t)(m0 + r0) * K1 + (ks - NS0) * 32 + s0 * 8;
      __builtin_amdgcn_global_load_lds(
          (const __attribute__((address_space(1))) void*)g0,
          (__attribute__((address_space(3))) void*)(&As[b][0][0] + (size_t)(w * 2 + 0) * 512),
          16, 0, 0);
      const __bf16* g1 = A1 + (size_t)(m0 + r1) * K1 + (ks - NS0) * 32 + s1 * 8;
      __builtin_amdgcn_global_load_lds(
          (const __attribute__((address_space(1))) void*)g1,
          (__attribute__((address_space(3))) void*)(&As[b][0][0] + (size_t)(w * 2 + 1) * 512),
          16, 0, 0);
    }
  };

  const int ml = lane & 15, q2 = lane >> 4;
  const int wr = (w >> 1) * 64;   // 0,64
  const int wc = (w & 1) * 64;    // 0,64

  f32x4 acc[4][4];
#pragma unroll
  for (int i = 0; i < 4; i++)
#pragma unroll
    for (int j = 0; j < 4; j++)
#pragma unroll
      for (int r = 0; r < 4; r++) acc[i][j][r] = 0.f;

  stage_step(0, 0);
  if (NS > 1) stage_step(1, 1);

#pragma unroll
  for (int ks = 0; ks < NS; ks++) {
    const int cur = ks & 1;
    if (ks + 1 < NS) asm volatile("s_waitcnt vmcnt(4)" ::: "memory");
    else             asm volatile("s_waitcnt vmcnt(0)" ::: "memory");
    asm volatile("s_barrier" ::: "memory");

    bf16x8 af[4], bfr[4];
#pragma unroll
    for (int i = 0; i < 4; i++)
      af[i] = *(const bf16x8*)(&As[cur][wr + i * 16 + ml][q2 * 8]);
#pragma unroll
    for (int j = 0; j < 4; j++)
      bfr[j] = *(const bf16x8*)(&Bs[cur][wc + j * 16 + ml][q2 * 8]);
#pragma unroll
    for (int i = 0; i < 4; i++)
#pragma unroll
      for (int j = 0; j < 4; j++)
        acc[i][j] = __builtin_amdgcn_mfma_f32_16x16x32_bf16(af[i], bfr[j],
                                                            acc[i][j], 0, 0, 0);

    asm volatile("s_barrier" ::: "memory");
    if (ks + 2 < NS) stage_step(cur, ks + 2);
  }

#pragma unroll
  for (int i = 0; i < 4; i++) {
#pragma unroll
    for (int r = 0; r < 4; r++) {
      int grow = m0 + wr + i * 16 + q2 * 4 + r;
      if (grow >= M) continue;
#pragma unroll
      for (int j = 0; j < 4; j++) {
        int col = bn0 + wc + j * 16 + ml;
        float v = acc[i][j][r];
        if (bias) v += bias[col];
        if (act) v = fast_tanh(v);
        if (Cb) Cb[(size_t)grow * Nc + col] = (__bf16)v;
        if (Cf) Cf[(size_t)grow * Nc + col] = v;
      }
    }
  }
}

extern "C" void kernel_launch(void* const* d_in, const int* in_sizes, int n_in,
                              void* d_out, int out_size, void* d_ws, size_t ws_size,
                              hipStream_t stream) {
  const float* feats  = (const float*)d_in[0];
  const int*   src    = (const int*)d_in[1];
  const int*   dst    = (const int*)d_in[2];
  const int*   etype  = (const int*)d_in[3];
  const float* W_in   = (const float*)d_in[4];
  const float* b_in   = (const float*)d_in[5];
  const float* W_rel  = (const float*)d_in[6];
  const float* W_loop = (const float*)d_in[7];
  const float* b_rel  = (const float*)d_in[8];
  const float* W_u1   = (const float*)d_in[9];
  const float* b_u1   = (const float*)d_in[10];
  const float* W_u2   = (const float*)d_in[11];
  const float* b_u2   = (const float*)d_in[12];

  const int E = in_sizes[1];
  const int N = in_sizes[0] / 64;
  const int TS = HID * HID;

  // --- workspace layout (~220 MB + ~10 MB tables) ---
  __bf16* xb0  = (__bf16*)d_ws;                       // N*128
  __bf16* xb1  = xb0 + (size_t)N * HID;               // N*128
  __bf16* msgb = xb1 + (size_t)N * HID;               // N*128
  __bf16* U    = msgb + (size_t)N * HID;              // N*640 (Zc | mid | featsb)
  __bf16* Z    = U;                                   // Zc: <=500K rows x 128
  __bf16* mid  = U;
  __bf16* featsb = U;
  __bf16* wt_in = U + (size_t)N * 640;                // [128][64]
  __bf16* wt_z  = wt_in + 128 * 64;                   // [10][8][128][128]
  __bf16* wt_u1 = wt_z + (size_t)10 * 8 * TS;         // [10][256][256]
  __bf16* wt_u2 = wt_u1 + (size_t)10 * 256 * 256;     // [10][128][384]
  int* rowCnt   = (int*)(wt_u2 + (size_t)10 * 128 * 384); // N
  int* rowStart = rowCnt + N;                         // N+1
  int* rowCur   = rowStart + N + 1;                   // N
  int* epk      = rowCur + N;                         // E
  int* thrPre   = epk + E;                            // 256*256
  int* blkSum   = thrPre + 256 * 256;                 // 256
  int* blkOff   = blkSum + 256;                       // 256
  int* F        = blkOff + 256;                       // 8N
  int* P        = F + 8 * N;                          // 8N+1
  int* S        = P + 8 * N + 1;                      // 8N

  // --- weight transpose+convert ---
  k_transpose<<<dim3(4, 2, 1), dim3(32, 8), 0, stream>>>(W_in, wt_in, 64, 128,
                                                         1, 1, 0, 1, 1, 0);
  // all 80 W_rel tiles, identity order: wt_z[l*8+r]
  k_transpose<<<dim3(4, 4, 80), dim3(32, 8), 0, stream>>>(W_rel, wt_z, 128, 128,
                                                          1, 1, 0, 1, 1, 0);
  k_transpose<<<dim3(8, 8, 10), dim3(32, 8), 0, stream>>>(W_u1, wt_u1, 256, 256,
                                                          1, 1, 0, 1, 1, 0);
  k_fold_wu1<<<dim3(8, 10), dim3(256), 0, stream>>>(W_u1, W_loop, wt_u1);
  k_transpose<<<dim3(4, 12, 10), dim3(32, 8), 0, stream>>>(W_u2, wt_u2, 384, 128,
                                                           1, 1, 0, 1, 1, 0);
  k_cvt<<<(N * 64 / 4 + 255) / 256, 256, 0, stream>>>(feats, featsb, N * 64 / 4);

  // --- dst-CSR + compaction tables ---
  k_zero<<<128, 256, 0, stream>>>(rowCnt, N);
  k_zero<<<512, 256, 0, stream>>>(F, 8 * N);
  k_hist_row<<<(E + 255) / 256, 256, 0, stream>>>(dst, E, rowCnt);
  k_flag<<<(E + 255) / 256, 256, 0, stream>>>(etype, src, E, N, F);
  // CSR row scan
  k_scan_part<<<256, 256, 0, stream>>>(rowCnt, N, thrPre, blkSum);
  k_scan_mid<<<1, 256, 0, stream>>>(blkSum, 256, N, blkOff, rowStart);
  k_scan_fin<<<256, 256, 0, stream>>>(rowCnt, N, thrPre, blkOff, rowStart, rowCur);
  // flag scan (rank table over 8N)
  k_scan_part<<<256, 256, 0, stream>>>(F, 8 * N, thrPre, blkSum);
  k_scan_mid<<<1, 256, 0, stream>>>(blkSum, 256, 8 * N, blkOff, P);
  k_scan_fin<<<256, 256, 0, stream>>>(F, 8 * N, thrPre, blkOff, P, nullptr);
  // gather table + edge placement
  k_srcof<<<(8 * N + 255) / 256, 256, 0, stream>>>(F, P, 8 * N, N, S);
  k_place_row<<<(E + 255) / 256, 256, 0, stream>>>(etype, src, dst, P,
                                                   rowCur, epk, E, N);

  const int gm = (N + 255) / 256;     // 256-row tiles
  const int gm128 = (N + 127) / 128;  // 128-row tiles
  const dim3 gseg((N + 15) / 16);

  // input projection: x0 = tanh(featsb @ W_in + b_in)
  gemm_lds128<64, 64, 2><<<dim3(1, gm128), dim3(256), 0, stream>>>(
      featsb, featsb, wt_in, b_in, xb0, nullptr, N, HID, 1);

  for (int l = 0; l < NL; l++) {
    const __bf16* xin = (l & 1) ? xb1 : xb0;
    __bf16* xout = (l & 1) ? xb0 : xb1;

    // gather pass (all 8 relations): Zc = x[srcOf] @ W_r
    gemm_gather<<<dim3(8, gm), dim3(512), 0, stream>>>(
        xin, wt_z + (size_t)l * 8 * TS, S, P, Z, N);
    // single seg: msg = b_rel + sum(all edges) Zc[zrow]
    seg_sum<<<gseg, dim3(256), 0, stream>>>(Z, rowStart, epk,
                                            b_rel + (size_t)l * HID, msgb, N);

    // mid = tanh([x | msg] @ Wu1_eff[l] + b_u1[l])   (mid aliases Zc; Zc dead)
    gemm_lds<256, 128, 2><<<dim3(2, gm), dim3(512), 0, stream>>>(
        xin, msgb, wt_u1 + (size_t)l * 256 * 256, b_u1 + (size_t)l * 256,
        mid, nullptr, N, 256, 1);

    // x' = tanh([x | mid] @ W_u2[l] + b_u2[l]); last layer -> f32 d_out
    gemm_lds128<384, 128, 2><<<dim3(1, gm128), dim3(256), 0, stream>>>(
        xin, mid, wt_u2 + (size_t)l * HID * 384, b_u2 + (size_t)l * HID,
        (l == NL - 1) ? nullptr : xout,
        (l == NL - 1) ? (float*)d_out : nullptr,
        N, HID, 1);
  }
}